// Round 13
// baseline (254.544 us; speedup 1.0000x reference)
//
#include <hip/hip_runtime.h>

typedef unsigned short bf_t;
typedef unsigned int u32;
typedef short short8 __attribute__((ext_vector_type(8)));
typedef float f32x4 __attribute__((ext_vector_type(4)));

#define NB 8
#define CC 128
#define NN 9216
#define EE 16
#define NT 144   // n-tiles per batch (9216/64)
#define HS 24    // hfT/vfT/ash padded row stride (48B: 16B-aligned, odd dword phase)

__device__ __forceinline__ float b2f(bf_t u){ return __uint_as_float(((u32)u)<<16); }
__device__ __forceinline__ bf_t f2b(float f){
  u32 u = __float_as_uint(f);
  u = (u + 0x7fffu + ((u>>16)&1u)) >> 16;
  return (bf_t)u;
}
__device__ __forceinline__ float gelu_f(float x){ return 0.5f*x*(1.f+erff(x*0.70710678118654752f)); }
__device__ __forceinline__ float red16(float v){
  #pragma unroll
  for (int m=1;m<16;m<<=1) v += __shfl_xor(v, m, 16);
  return v;
}
__device__ __forceinline__ float grs(float var){
  return rsqrtf(fmaxf(var + 1e-5f, 1e-8f));
}
// 8 consecutive fp32 -> bf16x8 MFMA fragment (works for global or LDS pointers)
__device__ __forceinline__ short8 ldw8(const float* __restrict__ p){
  float4 a = *(const float4*)p;
  float4 b = *(const float4*)(p+4);
  short8 o;
  o[0]=(short)f2b(a.x); o[1]=(short)f2b(a.y); o[2]=(short)f2b(a.z); o[3]=(short)f2b(a.w);
  o[4]=(short)f2b(b.x); o[5]=(short)f2b(b.y); o[6]=(short)f2b(b.z); o[7]=(short)f2b(b.w);
  return o;
}

// ---------------- zero hacc (+ optional weight pre-convert) ----------------
// MODE 0: zero only. MODE 1: + gate/nproj weights. MODE 2: + all edge weights.
template<int MODE>
__global__ __launch_bounds__(256) void k_pre(float* __restrict__ hacc,
    const float* __restrict__ gw, const float* __restrict__ npw,
    bf_t* __restrict__ gwb, bf_t* __restrict__ npwb,
    const float* __restrict__ w_in, const float* __restrict__ w_out,
    const float* __restrict__ w1, const float* __restrict__ w2,
    const float* __restrict__ hpw, const float* __restrict__ kvw,
    const float* __restrict__ qw,
    bf_t* __restrict__ w_in_b, bf_t* __restrict__ w_out_b,
    bf_t* __restrict__ w1_b, bf_t* __restrict__ w2_b,
    bf_t* __restrict__ hpw_b, bf_t* __restrict__ kvw_b,
    bf_t* __restrict__ qwT_b){
  int i = blockIdx.x*256 + threadIdx.x;     // 64 blocks -> 16384
  hacc[i] = 0.f;
  if (MODE >= 1){
    gwb[i]       = f2b(gw[i]);
    gwb[i+16384] = f2b(gw[i+16384]);
    npwb[i]      = f2b(npw[i]);
  }
  if (MODE == 2){
    #pragma unroll
    for (int k=0;k<3;k++) w_in_b[i + k*16384] = f2b(w_in[i + k*16384]);
    w_out_b[i]       = f2b(w_out[i]);
    w1_b[i]          = f2b(w1[i]);
    w1_b[i+16384]    = f2b(w1[i+16384]);
    w2_b[i]          = f2b(w2[i]);
    w2_b[i+16384]    = f2b(w2[i+16384]);
    hpw_b[i]         = f2b(hpw[i]);
    kvw_b[i]         = f2b(kvw[i]);
    kvw_b[i+16384]   = f2b(kvw[i+16384]);
    // transposed: qwT[c*128 + d] = qw[d*128 + c]
    qwT_b[i]         = f2b(qw[(i&127)*128 + (i>>7)]);
  }
}

// ---- node LN (over c) + fused hyperedge aggregation (MFMA agg) ----
// BFOUT=1: write LN'd nodes as bf16 [b][n][c] to nlnb. BFOUT=0: f32 c-major to nln.
template<int BFOUT, int AGG>
__global__ __launch_bounds__(256,4) void k_ln_agg(const float* __restrict__ fm,
                                                  const float* __restrict__ g,
                                                  const float* __restrict__ bb,
                                                  const float* __restrict__ sc,
                                                  float* __restrict__ nln,
                                                  bf_t* __restrict__ nlnb,
                                                  float* __restrict__ hacc){
  int b = blockIdx.y, n0 = blockIdx.x*64, tid = threadIdx.x;
  int lane = tid&63, wid = tid>>6, m16 = lane&15, quad = lane>>4;
  __shared__ float xs[128*65];              // [c][n] tile, pad 65
  __shared__ float scs[64][17];             // [n][e]
  __shared__ float ps[4][64], pq[4][64], mrs[2][64];
  const float* base = fm + (size_t)b*CC*NN + n0;
  #pragma unroll
  for (int p=0;p<8;p++){
    int idx = tid + p*256;                  // 0..2047 float4s
    int c = idx>>4, n4 = (idx&15)*4;
    float4 v = *(const float4*)(base + (size_t)c*NN + n4);
    xs[c*65 + n4+0] = v.x; xs[c*65 + n4+1] = v.y;
    xs[c*65 + n4+2] = v.z; xs[c*65 + n4+3] = v.w;
  }
  if (AGG){
    int n = tid>>2, e4 = (tid&3)*4;
    float4 sv = *(const float4*)(sc + ((size_t)(b*NN + n0 + n))*EE + e4);
    scs[n][e4+0] = sv.x; scs[n][e4+1] = sv.y;
    scs[n][e4+2] = sv.z; scs[n][e4+3] = sv.w;
  }
  __syncthreads();
  { int cg = tid>>6, n = tid&63;
    float s=0.f, q=0.f;
    #pragma unroll
    for (int c=0;c<32;c++){ float v = xs[(cg*32+c)*65 + n]; s+=v; q+=v*v; }
    ps[cg][n]=s; pq[cg][n]=q;
  }
  __syncthreads();
  if (tid < 64){
    float S = ps[0][tid]+ps[1][tid]+ps[2][tid]+ps[3][tid];
    float Q = pq[0][tid]+pq[1][tid]+pq[2][tid]+pq[3][tid];
    float m = S*(1.f/128.f);
    mrs[0][tid] = m; mrs[1][tid] = grs(Q*(1.f/128.f) - m*m);
  }
  __syncthreads();
  #pragma unroll
  for (int p=0;p<8;p++){
    int idx = tid + p*256;
    int c = idx>>4, n4 = (idx&15)*4;
    float gv = g[c], bv = bb[c];
    float v0 = (xs[c*65+n4+0]-mrs[0][n4+0])*mrs[1][n4+0]*gv + bv;
    float v1 = (xs[c*65+n4+1]-mrs[0][n4+1])*mrs[1][n4+1]*gv + bv;
    float v2 = (xs[c*65+n4+2]-mrs[0][n4+2])*mrs[1][n4+2]*gv + bv;
    float v3 = (xs[c*65+n4+3]-mrs[0][n4+3])*mrs[1][n4+3]*gv + bv;
    xs[c*65+n4+0]=v0; xs[c*65+n4+1]=v1; xs[c*65+n4+2]=v2; xs[c*65+n4+3]=v3;
    if (!BFOUT){
      float4 o; o.x=v0; o.y=v1; o.z=v2; o.w=v3;
      *(float4*)(nln + ((size_t)(b*CC + c))*NN + n0 + n4) = o;
    }
  }
  __syncthreads();
  if (BFOUT){
    // bf16 [n][c] store: coalesced 16B/lane rows
    #pragma unroll
    for (int p=0;p<4;p++){
      int idx = tid + p*256;                // 0..1023
      int n = idx>>4, c8 = (idx&15)*8;
      short8 o;
      #pragma unroll
      for (int j=0;j<8;j++) o[j] = (short)f2b(xs[(c8+j)*65 + n]);
      *(short8*)(nlnb + ((size_t)(b*NN + n0 + n))*CC + c8) = o;
    }
  }
  if (AGG){
    // sc^T @ xln via MFMA: D[e][c] += sum_n sc[n][e]*xln[c][n], K=64.
    // Same operand convention as gemm16 (verified): A row=m16,k=quad*8+j;
    // B row=m16,k; D col=m16,row=quad*4+r. Replaces 512 scalar FMA + 128
    // scalar LDS reads per thread with 4 MFMAs + 32 LDS reads per wave.
    short8 afr[2];
    #pragma unroll
    for (int k0=0;k0<2;k0++){
      short8 t;
      #pragma unroll
      for (int j=0;j<8;j++) t[j] = (short)f2b(scs[k0*32 + quad*8 + j][m16]);
      afr[k0] = t;
    }
    #pragma unroll
    for (int u=0;u<2;u++){
      int ct0 = (wid + u*4)*16;             // c-tile base: 8 tiles over 4 waves x 2
      f32x4 acc = {0.f,0.f,0.f,0.f};
      #pragma unroll
      for (int k0=0;k0<2;k0++){
        short8 bfr = ldw8(&xs[(ct0+m16)*65 + k0*32 + quad*8]);
        acc = __builtin_amdgcn_mfma_f32_16x16x32_bf16(afr[k0], bfr, acc, 0, 0, 0);
      }
      float* hb = hacc + ((size_t)(b*EE + quad*4))*CC + ct0 + m16;
      #pragma unroll
      for (int r=0;r<4;r++)
        atomicAdd(hb + (size_t)r*CC, acc[r]);
    }
  }
}

// ------- in-LDS 16-row MFMA GEMM helper (NW waves, tile-strided) -------
template<int K, int NOUT, int ACT, int WB, int NW>
__device__ __forceinline__ void gemm16(const bf_t* A, int SA,
                                       const float* __restrict__ W,
                                       const bf_t* __restrict__ Wb,
                                       const float* __restrict__ bias,
                                       bf_t* O, int SO, int tid){
  int lane = tid&63, wid = tid>>6;
  int m16 = lane&15, quad = lane>>4;
  for (int t0 = wid; t0 < NOUT/16; t0 += NW){
    int n0 = t0*16;
    f32x4 acc = {0.f,0.f,0.f,0.f};
    #pragma unroll
    for (int k0=0;k0<K;k0+=32){
      short8 af = *(const short8*)(A + m16*SA + k0 + quad*8);
      short8 bfv = WB ? *(const short8*)(Wb + (size_t)(n0+m16)*K + k0 + quad*8)
                      : ldw8(W + (size_t)(n0+m16)*K + k0 + quad*8);
      acc = __builtin_amdgcn_mfma_f32_16x16x32_bf16(af, bfv, acc, 0, 0, 0);
    }
    int col = n0 + m16;
    float bv = bias[col];
    #pragma unroll
    for (int r=0;r<4;r++){
      float v = acc[r] + bv;
      if (ACT) v = gelu_f(v);
      O[(quad*4+r)*SO + col] = f2b(v);
    }
  }
}

#define SP1 136
#define SP2 264
#define SP3 392

// -------- edge transformer (per batch), 512 threads = 8 waves --------
template<int WB>
__global__ __launch_bounds__(512) void k_edge(const float* __restrict__ hacc,
    const float* w_in, const float* b_in, const float* w_out, const float* b_out,
    const float* w1, const float* b1, const float* w2, const float* b2v,
    const float* tg, const float* tb, const float* nhg, const float* nhb,
    const float* hpw, const float* hpb, const float* kvw, const float* kvbias,
    const float* qw, const float* qb,
    const bf_t* __restrict__ w_in_b, const bf_t* __restrict__ w_out_b,
    const bf_t* __restrict__ w1_b, const bf_t* __restrict__ w2_b,
    const bf_t* __restrict__ hpw_b, const bf_t* __restrict__ kvw_b,
    const bf_t* __restrict__ qwT_b,
    bf_t* __restrict__ hfw, bf_t* __restrict__ vws,
    bf_t* __restrict__ Ktgb, float* __restrict__ qbK){
  __shared__ __align__(16) bf_t hyp0[16*SP1];
  __shared__ __align__(16) bf_t qkvb[16*SP3];
  __shared__ __align__(16) bf_t aob [16*SP1];
  __shared__ __align__(16) bf_t xnb [16*SP1];
  __shared__ __align__(16) bf_t h1b [16*SP2];
  __shared__ __align__(16) bf_t t2b [16*SP1];
  __shared__ __align__(16) bf_t hfb [16*SP1];
  __shared__ __align__(16) bf_t kvo [16*SP2];
  int b = blockIdx.x, tid = threadIdx.x;
  int lane = tid&63, wid = tid>>6, m16 = lane&15, quad = lane>>4;

  #pragma unroll
  for (int p=0;p<4;p++){
    int idx = tid + p*512;                  // 0..2047
    int e = idx>>7, c = idx&127;
    hyp0[e*SP1 + c] = f2b(hacc[(size_t)(b*EE + e)*CC + c]);
  }
  __syncthreads();
  gemm16<128,384,0,WB,8>(hyp0, SP1, w_in, w_in_b, b_in, qkvb, SP3, tid);
  __syncthreads();
  if (tid < 256){
    int part = tid&3, hq = tid>>2;
    int h = hq>>4, qi = hq&15;
    int dbase = h*32 + part*8;
    float qv[8];
    #pragma unroll
    for (int j=0;j<8;j++) qv[j] = b2f(qkvb[qi*SP3 + dbase + j]);
    float dot[16];
    #pragma unroll
    for (int kk=0;kk<16;kk++){
      float s = 0.f;
      #pragma unroll
      for (int j=0;j<8;j++) s += qv[j]*b2f(qkvb[kk*SP3 + 128 + dbase + j]);
      dot[kk] = s;
    }
    #pragma unroll
    for (int m=1;m<4;m<<=1){
      #pragma unroll
      for (int kk=0;kk<16;kk++) dot[kk] += __shfl_xor(dot[kk], m, 4);
    }
    const float sc1 = 0.17677669529663687f;
    float mx = -1e30f;
    #pragma unroll
    for (int kk=0;kk<16;kk++){ dot[kk] *= sc1; mx = fmaxf(mx, dot[kk]); }
    float sum = 0.f;
    #pragma unroll
    for (int kk=0;kk<16;kk++){ dot[kk] = __expf(dot[kk]-mx); sum += dot[kk]; }
    float inv = 1.f/sum;
    float ao[8] = {0,0,0,0,0,0,0,0};
    #pragma unroll
    for (int kk=0;kk<16;kk++){
      float p = dot[kk]*inv;
      #pragma unroll
      for (int j=0;j<8;j++) ao[j] += p*b2f(qkvb[kk*SP3 + 256 + dbase + j]);
    }
    #pragma unroll
    for (int j=0;j<8;j++) aob[qi*SP1 + dbase + j] = f2b(ao[j]);
  }
  __syncthreads();
  gemm16<128,128,0,WB,8>(aob, SP1, w_out, w_out_b, b_out, xnb, SP1, tid);
  __syncthreads();
  if (tid < 256){
    int e = tid>>4, i = tid&15;
    float v[8]; float s=0.f, q=0.f;
    #pragma unroll
    for (int j=0;j<8;j++){
      int c = i*8+j;
      v[j] = b2f(hyp0[e*SP1+c]) + b2f(xnb[e*SP1+c]);
      s += v[j]; q += v[j]*v[j];
    }
    s = red16(s); q = red16(q);
    float m = s*(1.f/128.f);
    float rs = grs(q*(1.f/128.f) - m*m);
    #pragma unroll
    for (int j=0;j<8;j++){
      int c = i*8+j;
      xnb[e*SP1+c] = f2b((v[j]-m)*rs*tg[c] + tb[c]);
    }
  }
  __syncthreads();
  gemm16<128,256,1,WB,8>(xnb, SP1, w1, w1_b, b1, h1b, SP2, tid);
  __syncthreads();
  gemm16<256,128,0,WB,8>(h1b, SP2, w2, w2_b, b2v, aob, SP1, tid);
  __syncthreads();
  if (tid < 256){
    int e = tid>>4, i = tid&15;
    float v[8]; float s=0.f, q=0.f;
    #pragma unroll
    for (int j=0;j<8;j++){
      int c = i*8+j;
      v[j] = b2f(xnb[e*SP1+c]) + b2f(aob[e*SP1+c]);
      s += v[j]; q += v[j]*v[j];
    }
    s = red16(s); q = red16(q);
    float m = s*(1.f/128.f);
    float rs = grs(q*(1.f/128.f) - m*m);
    float s2=0.f, q2=0.f;
    #pragma unroll
    for (int j=0;j<8;j++){
      int c = i*8+j;
      v[j] = (v[j]-m)*rs*tg[c] + tb[c];
      s2 += v[j]; q2 += v[j]*v[j];
    }
    s2 = red16(s2); q2 = red16(q2);
    float m2 = s2*(1.f/128.f);
    float rs2 = grs(q2*(1.f/128.f) - m2*m2);
    #pragma unroll
    for (int j=0;j<8;j++){
      int c = i*8+j;
      t2b[e*SP1+c] = f2b((v[j]-m2)*rs2*nhg[c] + nhb[c]);
    }
  }
  __syncthreads();
  gemm16<128,128,1,WB,8>(t2b, SP1, hpw, hpw_b, hpb, hfb, SP1, tid);
  __syncthreads();
  gemm16<128,256,0,WB,8>(hfb, SP1, kvw, kvw_b, kvbias, kvo, SP2, tid);
  __syncthreads();
  #pragma unroll
  for (int p=0;p<4;p++){
    int idx = tid + p*512;
    int e = idx>>7, c = idx&127;
    size_t o = (size_t)(b*EE + e)*CC + c;
    hfw[o] = hfb[e*SP1 + c];
    vws[o] = kvo[e*SP2 + 128 + c];
  }
  // Kt[e][c] = sum_d K[e][d]*qw[d][c] via MFMA, bf16 out (8 waves: 1 pass)
  {
    int n0 = wid*16;
    f32x4 acc = {0.f,0.f,0.f,0.f};
    #pragma unroll
    for (int k0=0;k0<128;k0+=32){
      short8 a = *(const short8*)(kvo + m16*SP2 + k0 + quad*8);
      short8 bq;
      if (WB){
        bq = *(const short8*)(qwT_b + (size_t)(n0+m16)*128 + k0 + quad*8);
      } else {
        #pragma unroll
        for (int j=0;j<8;j++)
          bq[j] = (short)f2b(qw[(size_t)(k0+quad*8+j)*128 + n0+m16]);
      }
      acc = __builtin_amdgcn_mfma_f32_16x16x32_bf16(a, bq, acc, 0, 0, 0);
    }
    #pragma unroll
    for (int r=0;r<4;r++)
      Ktgb[(size_t)(b*EE + quad*4 + r)*CC + n0 + m16] = f2b(acc[r]);
  }
  // qbK[e] = qb . K[e]
  if (tid < 256){
    int e = tid>>4, i = tid&15;
    float s = 0.f;
    #pragma unroll
    for (int j=0;j<8;j++) s += qb[i*8+j]*b2f(kvo[e*SP2 + i*8+j]);
    s = red16(s);
    if (i == 0) qbK[b*EE + e] = s;
  }
}

// -------- mega node kernel, 46.3 KB LDS; tail recompute-fuse (R10 best) --------
template<int MODE>
__global__ __launch_bounds__(256,3) void k_meganode(
    float* __restrict__ io, const bf_t* __restrict__ nlnb,
    const float* __restrict__ sc,
    const bf_t* __restrict__ hf, const bf_t* __restrict__ vw,
    const bf_t* __restrict__ ktg, const float* __restrict__ qbK,
    const float* __restrict__ nfg, const float* __restrict__ nfb,
    const float* __restrict__ gw, const bf_t* __restrict__ gwb,
    const float* __restrict__ gb,
    const float* __restrict__ glng, const float* __restrict__ glnb,
    const float* __restrict__ npw, const bf_t* __restrict__ npwb,
    const float* __restrict__ npb){
  int tid = threadIdx.x, lane = tid&63, wid = tid>>6;
  int m16 = lane&15, quad = lane>>4;
  int b = blockIdx.y, n0 = blockIdx.x*64;
  __shared__ __align__(16) char sm[46336];
  bf_t* xt  = (bf_t*)(sm);            // [64][136] 17,408
  bf_t* ktT = (bf_t*)(sm + 17408);    // [16][136]  4,352 (dead after QK^T)
  bf_t* hfT = (bf_t*)(sm + 21760);    // [128][HS]  6,144 (LIVE to end: fuse recompute)
  bf_t* vfT = (bf_t*)(sm + 27904);    // [128][HS]  6,144 (LIVE to end)
  bf_t* ash = (bf_t*)(sm + 34048);    // [64][HS]   3,072
  bf_t* ct  = (bf_t*)(sm + 37120);    // [64][72]   9,216 (fresh; no live overlay)
  const short8 z8 = {0,0,0,0,0,0,0,0};

  // ---- staging ----
  if (MODE == 2){
    const bf_t* nb = nlnb + ((size_t)(b*NN + n0))*CC;
    #pragma unroll
    for (int p=0;p<4;p++){
      int idx = tid + p*256;                      // 0..1023
      int n = idx>>4, c8 = (idx&15)*8;
      *(short8*)&xt[n*136 + c8] = *(const short8*)(nb + (size_t)n*CC + c8);
    }
  } else {
    #pragma unroll
    for (int p=0;p<8;p++){
      int idx = tid + p*256;
      int c = idx>>4, n4 = (idx&15)*4;
      float4 v = *(const float4*)(io + ((size_t)(b*CC + c))*NN + n0 + n4);
      xt[(n4+0)*136 + c] = f2b(v.x);
      xt[(n4+1)*136 + c] = f2b(v.y);
      xt[(n4+2)*136 + c] = f2b(v.z);
      xt[(n4+3)*136 + c] = f2b(v.w);
    }
  }
  { const u32* kp = (const u32*)(ktg + (size_t)b*EE*CC);
    #pragma unroll
    for (int p=0;p<4;p++){
      int idx = tid + p*256;
      int e = idx>>6, c2 = (idx&63)*2;
      *(u32*)&ktT[e*136 + c2] = kp[idx];
    }
  }
  { const u32* hs = (const u32*)(hf + (size_t)b*EE*CC);
    const u32* vs = (const u32*)(vw + (size_t)b*EE*CC);
    #pragma unroll
    for (int p=0;p<4;p++){
      int idx = tid + p*256;
      int e = idx>>6, c2 = (idx&63)*2;
      u32 hv = hs[idx], vv = vs[idx];
      hfT[(c2+0)*HS + e] = (bf_t)(hv&0xffffu);
      hfT[(c2+1)*HS + e] = (bf_t)(hv>>16);
      vfT[(c2+0)*HS + e] = (bf_t)(vv&0xffffu);
      vfT[(c2+1)*HS + e] = (bf_t)(vv>>16);
    }
  }
  __syncthreads();

  // ---- QK^T via MFMA: D[node][e]; softmax over e ----
  f32x4 dacc = {0.f,0.f,0.f,0.f};
  #pragma unroll
  for (int kk=0;kk<4;kk++){
    short8 a = *(const short8*)(xt + (wid*16+m16)*136 + kk*32 + quad*8);
    short8 bfr = *(const short8*)(ktT + m16*136 + kk*32 + quad*8);
    dacc = __builtin_amdgcn_mfma_f32_16x16x32_bf16(a, bfr, dacc, 0, 0, 0);
  }
  { float qbe = qbK[b*EE + m16];
    #pragma unroll
    for (int r=0;r<4;r++){
      float v = (dacc[r] + qbe) * 0.08838834764831845f;   // C^-0.5
      float m = v;
      #pragma unroll
      for (int msk=1;msk<16;msk<<=1) m = fmaxf(m, __shfl_xor(m, msk, 16));
      float ex = __expf(v - m);
      float s = ex;
      #pragma unroll
      for (int msk=1;msk<16;msk<<=1) s += __shfl_xor(s, msk, 16);
      ash[(wid*16 + quad*4 + r)*HS + m16] = f2b(ex / s);
    }
  }

  // ---- intra = sc@hf, cross = a@vf via MFMA (K=16 in lower half) ----
  short8 scf = z8, asf = z8;
  if (quad < 2){
    const float* sp = sc + ((size_t)(b*NN + n0 + wid*16 + m16))*EE + quad*8;
    float4 u0 = *(const float4*)sp;
    float4 u1 = *(const float4*)(sp+4);
    scf[0]=(short)f2b(u0.x); scf[1]=(short)f2b(u0.y); scf[2]=(short)f2b(u0.z); scf[3]=(short)f2b(u0.w);
    scf[4]=(short)f2b(u1.x); scf[5]=(short)f2b(u1.y); scf[6]=(short)f2b(u1.z); scf[7]=(short)f2b(u1.w);
    asf = *(const short8*)(ash + (wid*16+m16)*HS + quad*8);
  }
  f32x4 acc_it[8], acc_cr[8];
  #pragma unroll
  for (int t=0;t<8;t++){
    short8 bh = z8, bv = z8;
    if (quad < 2){
      bh = *(const short8*)(hfT + (t*16+m16)*HS + quad*8);
      bv = *(const short8*)(vfT + (t*16+m16)*HS + quad*8);
    }
    f32x4 zf = {0.f,0.f,0.f,0.f};
    acc_it[t] = __builtin_amdgcn_mfma_f32_16x16x32_bf16(scf, bh, zf, 0, 0, 0);
    acc_cr[t] = __builtin_amdgcn_mfma_f32_16x16x32_bf16(asf, bv, zf, 0, 0, 0);
  }

  // ---- concat-LN stats (256 chans/node) ----
  float mean4[4], rstd4[4];
  { float s4[4]={0,0,0,0}, q4[4]={0,0,0,0};
    #pragma unroll
    for (int t=0;t<8;t++)
      #pragma unroll
      for (int r=0;r<4;r++){
        float a = acc_it[t][r], c = acc_cr[t][r];
        s4[r] += a + c; q4[r] += a*a + c*c;
      }
    #pragma unroll
    for (int r=0;r<4;r++){
      s4[r] = red16(s4[r]); q4[r] = red16(q4[r]);
      mean4[r] = s4[r]*(1.f/256.f);
      rstd4[r] = grs(q4[r]*(1.f/256.f) - mean4[r]*mean4[r]);
    }
  }
  __syncthreads();
  // ---- gate A fragments via ct [64][72], 64-channel sub-passes ----
  // after af is built, acc_it/acc_cr are DEAD (fuse recomputes them).
  short8 af[8];
  #pragma unroll
  for (int s=0;s<2;s++){
    #pragma unroll
    for (int r=0;r<4;r++){
      int node = wid*16 + quad*4 + r;
      #pragma unroll
      for (int t=0;t<4;t++){
        int ch = (s*4+t)*16 + m16;
        ct[node*72 + t*16 + m16] = f2b((acc_it[s*4+t][r]-mean4[r])*rstd4[r]*nfg[ch] + nfb[ch]);
      }
    }
    #pragma unroll
    for (int k2=0;k2<2;k2++)
      af[s*2+k2] = *(const short8*)(ct + (wid*16+m16)*72 + k2*32 + quad*8);
  }
  #pragma unroll
  for (int s=0;s<2;s++){
    #pragma unroll
    for (int r=0;r<4;r++){
      int node = wid*16 + quad*4 + r;
      #pragma unroll
      for (int t=0;t<4;t++){
        int ch = (s*4+t)*16 + m16;
        ct[node*72 + t*16 + m16] = f2b((acc_cr[s*4+t][r]-mean4[r])*rstd4[r]*nfg[128+ch] + nfb[128+ch]);
      }
    }
    #pragma unroll
    for (int k2=0;k2<2;k2++)
      af[4+s*2+k2] = *(const short8*)(ct + (wid*16+m16)*72 + k2*32 + quad*8);
  }

  // ---- gate GEMM (K=256) ----
  f32x4 acc_g[8];
  #pragma unroll
  for (int t=0;t<8;t++){
    f32x4 a = {0.f,0.f,0.f,0.f};
    #pragma unroll
    for (int kk=0;kk<8;kk++){
      short8 w8 = (MODE >= 1) ? *(const short8*)(gwb + (size_t)(t*16+m16)*256 + kk*32 + quad*8)
                              : ldw8(gw + (size_t)(t*16+m16)*256 + kk*32 + quad*8);
      a = __builtin_amdgcn_mfma_f32_16x16x32_bf16(af[kk], w8, a, 0, 0, 0);
    }
    acc_g[t] = a;
  }

  // ---- gate bias + gate-LN stats ----
  float m2r[4], rs2r[4];
  { float s2[4]={0,0,0,0}, q2[4]={0,0,0,0};
    #pragma unroll
    for (int t=0;t<8;t++){
      float bv = gb[t*16+m16];
      #pragma unroll
      for (int r=0;r<4;r++){
        float v = acc_g[t][r] + bv;
        acc_g[t][r] = v; s2[r] += v; q2[r] += v*v;
      }
    }
    #pragma unroll
    for (int r=0;r<4;r++){
      s2[r] = red16(s2[r]); q2[r] = red16(q2[r]);
      m2r[r] = s2[r]*(1.f/128.f);
      rs2r[r] = grs(q2[r]*(1.f/128.f) - m2r[r]*m2r[r]);
    }
  }

  // ---- fuse: recompute it/cr per t (bitwise-identical MFMA), sigmoid gate,
  //      residual -> upd into xt ----
  #pragma unroll
  for (int t=0;t<8;t++){
    short8 bh = z8, bv = z8;
    if (quad < 2){
      bh = *(const short8*)(hfT + (t*16+m16)*HS + quad*8);
      bv = *(const short8*)(vfT + (t*16+m16)*HS + quad*8);
    }
    f32x4 zf = {0.f,0.f,0.f,0.f};
    f32x4 itR = __builtin_amdgcn_mfma_f32_16x16x32_bf16(scf, bh, zf, 0, 0, 0);
    f32x4 crR = __builtin_amdgcn_mfma_f32_16x16x32_bf16(asf, bv, zf, 0, 0, 0);
    int col = t*16 + m16;
    float lg = glng[col], lb = glnb[col];
    #pragma unroll
    for (int r=0;r<4;r++){
      float z = (acc_g[t][r]-m2r[r])*rs2r[r]*lg + lb;
      float gs = 1.f/(1.f + __expf(-z));
      int node = wid*16 + quad*4 + r;
      float nld = b2f(xt[node*136 + col]);
      xt[node*136 + col] = f2b(nld + gs*itR[r] + (1.f-gs)*crR[r]);
    }
  }

  // ---- output projection: frags from xt (wave-private rows), direct stores ----
  short8 bfu[4];
  #pragma unroll
  for (int kk=0;kk<4;kk++)
    bfu[kk] = *(const short8*)(xt + (wid*16+m16)*136 + kk*32 + quad*8);
  #pragma unroll
  for (int mt=0;mt<8;mt++){
    f32x4 o = {0.f,0.f,0.f,0.f};
    #pragma unroll
    for (int kk=0;kk<4;kk++){
      short8 aw = (MODE >= 1) ? *(const short8*)(npwb + (size_t)(mt*16+m16)*128 + kk*32 + quad*8)
                              : ldw8(npw + (size_t)(mt*16+m16)*128 + kk*32 + quad*8);
      o = __builtin_amdgcn_mfma_f32_16x16x32_bf16(aw, bfu[kk], o, 0, 0, 0);
    }
    #pragma unroll
    for (int r=0;r<4;r++){
      int cp = mt*16 + quad*4 + r;
      io[((size_t)(b*CC + cp))*NN + n0 + wid*16 + m16] = gelu_f(o[r] + npb[cp]);
    }
  }
}

extern "C" void kernel_launch(void* const* d_in, const int* in_sizes, int n_in,
                              void* d_out, int out_size, void* d_ws, size_t ws_size,
                              hipStream_t stream){
  (void)in_sizes; (void)n_in; (void)out_size;
  const float* fm   = (const float*)d_in[0];
  const float* sc   = (const float*)d_in[1];
  const float* npg  = (const float*)d_in[2];
  const float* npb_ = (const float*)d_in[3];
  const float* w_in = (const float*)d_in[4];
  const float* b_in = (const float*)d_in[5];
  const float* w_out= (const float*)d_in[6];
  const float* b_out= (const float*)d_in[7];
  const float* w1   = (const float*)d_in[8];
  const float* b1   = (const float*)d_in[9];
  const float* w2   = (const float*)d_in[10];
  const float* b2v  = (const float*)d_in[11];
  const float* tg   = (const float*)d_in[12];
  const float* tb   = (const float*)d_in[13];
  const float* nhg  = (const float*)d_in[14];
  const float* nhb  = (const float*)d_in[15];
  const float* hpw  = (const float*)d_in[16];
  const float* hpb  = (const float*)d_in[17];
  const float* qw   = (const float*)d_in[18];
  const float* qb   = (const float*)d_in[19];
  const float* kvw  = (const float*)d_in[20];
  const float* kvb  = (const float*)d_in[21];
  const float* nfg  = (const float*)d_in[22];
  const float* nfb  = (const float*)d_in[23];
  const float* gw   = (const float*)d_in[24];
  const float* gb   = (const float*)d_in[25];
  const float* glng = (const float*)d_in[26];
  const float* glnb = (const float*)d_in[27];
  const float* npw  = (const float*)d_in[28];
  const float* npb2 = (const float*)d_in[29];

  float* nln = (float*)d_out;   // fallback: f32 node tensor c-major lives in d_out

  // ws layout
  char* w = (char*)d_ws;
  float* hacc    = (float*)(w);             //  65,536 B
  float* qbK     = (float*)(w + 65536);     //     512 B
  bf_t*  hfw     = (bf_t*) (w + 66048);     //  32,768 B
  bf_t*  vws     = (bf_t*) (w + 98816);     //  32,768 B
  bf_t*  Ktgb    = (bf_t*) (w + 131584);    //  32,768 B (end 164,352)
  bf_t*  gwb     = (bf_t*) (w + 164352);    //  65,536 B
  bf_t*  npwb    = (bf_t*) (w + 229888);    //  32,768 B (end 262,656)
  bf_t*  w_in_b  = (bf_t*) (w + 262656);    //  98,304 B
  bf_t*  w_out_b = (bf_t*) (w + 360960);    //  32,768 B
  bf_t*  w1_b    = (bf_t*) (w + 393728);    //  65,536 B
  bf_t*  w2_b    = (bf_t*) (w + 459264);    //  65,536 B
  bf_t*  hpw_b   = (bf_t*) (w + 524800);    //  32,768 B
  bf_t*  kvw_b   = (bf_t*) (w + 557568);    //  65,536 B
  bf_t*  qwT_b   = (bf_t*) (w + 623104);    //  32,768 B (end 655,872)
  bf_t*  nlnb    = (bf_t*) (w + 655872);    // 18,874,368 B (end 19,530,240)
  bool full  = (ws_size >= (size_t)19530240);
  bool pre   = (ws_size >= (size_t)262656);

  if (full){
    k_pre<2><<<dim3(64), dim3(256), 0, stream>>>(hacc, gw, npw, gwb, npwb,
        w_in, w_out, w1, w2, hpw, kvw, qw,
        w_in_b, w_out_b, w1_b, w2_b, hpw_b, kvw_b, qwT_b);
    k_ln_agg<1,1><<<dim3(NT,8), dim3(256), 0, stream>>>(fm, npg, npb_, sc, nln, nlnb, hacc);
    k_edge<1><<<dim3(8), dim3(512), 0, stream>>>(hacc, w_in,b_in,w_out,b_out,
        w1,b1,w2,b2v, tg,tb, nhg,nhb, hpw,hpb, kvw,kvb, qw,qb,
        w_in_b, w_out_b, w1_b, w2_b, hpw_b, kvw_b, qwT_b,
        hfw, vws, Ktgb, qbK);
    k_meganode<2><<<dim3(NT,8), dim3(256), 0, stream>>>(nln, nlnb, sc, hfw, vws, Ktgb, qbK,
        nfg, nfb, gw, gwb, gb, glng, glnb, npw, npwb, npb2);
  } else if (pre){
    k_pre<1><<<dim3(64), dim3(256), 0, stream>>>(hacc, gw, npw, gwb, npwb,
        w_in, w_out, w1, w2, hpw, kvw, qw,
        w_in_b, w_out_b, w1_b, w2_b, hpw_b, kvw_b, qwT_b);
    k_ln_agg<0,1><<<dim3(NT,8), dim3(256), 0, stream>>>(fm, npg, npb_, sc, nln, nlnb, hacc);
    k_edge<0><<<dim3(8), dim3(512), 0, stream>>>(hacc, w_in,b_in,w_out,b_out,
        w1,b1,w2,b2v, tg,tb, nhg,nhb, hpw,hpb, kvw,kvb, qw,qb,
        w_in_b, w_out_b, w1_b, w2_b, hpw_b, kvw_b, qwT_b,
        hfw, vws, Ktgb, qbK);
    k_meganode<1><<<dim3(NT,8), dim3(256), 0, stream>>>(nln, nlnb, sc, hfw, vws, Ktgb, qbK,
        nfg, nfb, gw, gwb, gb, glng, glnb, npw, npwb, npb2);
  } else {
    k_pre<0><<<dim3(64), dim3(256), 0, stream>>>(hacc, gw, npw, gwb, npwb,
        w_in, w_out, w1, w2, hpw, kvw, qw,
        w_in_b, w_out_b, w1_b, w2_b, hpw_b, kvw_b, qwT_b);
    k_ln_agg<0,1><<<dim3(NT,8), dim3(256), 0, stream>>>(fm, npg, npb_, sc, nln, nlnb, hacc);
    k_edge<0><<<dim3(8), dim3(512), 0, stream>>>(hacc, w_in,b_in,w_out,b_out,
        w1,b1,w2,b2v, tg,tb, nhg,nhb, hpw,hpb, kvw,kvb, qw,qb,
        w_in_b, w_out_b, w1_b, w2_b, hpw_b, kvw_b, qwT_b,
        hfw, vws, Ktgb, qbK);
    k_meganode<0><<<dim3(NT,8), dim3(256), 0, stream>>>(nln, nlnb, sc, hfw, vws, Ktgb, qbK,
        nfg, nfb, gw, gwb, gb, glng, glnb, npw, npwb, npb2);
  }
}

// Round 14
// 252.383 us; speedup vs baseline: 1.0086x; 1.0086x over previous
//
#include <hip/hip_runtime.h>

typedef unsigned short bf_t;
typedef unsigned int u32;
typedef short short8 __attribute__((ext_vector_type(8)));
typedef float f32x4 __attribute__((ext_vector_type(4)));

#define NB 8
#define CC 128
#define NN 9216
#define EE 16
#define NT 144   // n-tiles per batch (9216/64)
#define HS 24    // hfT/vfT/ash padded row stride (48B: 16B-aligned, odd dword phase)
#define XR 72    // ln_agg xs row stride in bf16 (144B: 16B-aligned rows)

__device__ __forceinline__ float b2f(bf_t u){ return __uint_as_float(((u32)u)<<16); }
__device__ __forceinline__ bf_t f2b(float f){
  u32 u = __float_as_uint(f);
  u = (u + 0x7fffu + ((u>>16)&1u)) >> 16;
  return (bf_t)u;
}
__device__ __forceinline__ float gelu_f(float x){ return 0.5f*x*(1.f+erff(x*0.70710678118654752f)); }
__device__ __forceinline__ float red16(float v){
  #pragma unroll
  for (int m=1;m<16;m<<=1) v += __shfl_xor(v, m, 16);
  return v;
}
__device__ __forceinline__ float grs(float var){
  return rsqrtf(fmaxf(var + 1e-5f, 1e-8f));
}
// 8 consecutive fp32 -> bf16x8 MFMA fragment (fallback / on-the-fly path)
__device__ __forceinline__ short8 ldw8(const float* __restrict__ p){
  float4 a = *(const float4*)p;
  float4 b = *(const float4*)(p+4);
  short8 o;
  o[0]=(short)f2b(a.x); o[1]=(short)f2b(a.y); o[2]=(short)f2b(a.z); o[3]=(short)f2b(a.w);
  o[4]=(short)f2b(b.x); o[5]=(short)f2b(b.y); o[6]=(short)f2b(b.z); o[7]=(short)f2b(b.w);
  return o;
}

// ---------------- zero hacc (+ optional weight pre-convert) ----------------
// MODE 0: zero only. MODE 1: + gate/nproj weights. MODE 2: + all edge weights.
template<int MODE>
__global__ __launch_bounds__(256) void k_pre(float* __restrict__ hacc,
    const float* __restrict__ gw, const float* __restrict__ npw,
    bf_t* __restrict__ gwb, bf_t* __restrict__ npwb,
    const float* __restrict__ w_in, const float* __restrict__ w_out,
    const float* __restrict__ w1, const float* __restrict__ w2,
    const float* __restrict__ hpw, const float* __restrict__ kvw,
    const float* __restrict__ qw,
    bf_t* __restrict__ w_in_b, bf_t* __restrict__ w_out_b,
    bf_t* __restrict__ w1_b, bf_t* __restrict__ w2_b,
    bf_t* __restrict__ hpw_b, bf_t* __restrict__ kvw_b,
    bf_t* __restrict__ qwT_b){
  int i = blockIdx.x*256 + threadIdx.x;     // 64 blocks -> 16384
  hacc[i] = 0.f;
  if (MODE >= 1){
    gwb[i]       = f2b(gw[i]);
    gwb[i+16384] = f2b(gw[i+16384]);
    npwb[i]      = f2b(npw[i]);
  }
  if (MODE == 2){
    #pragma unroll
    for (int k=0;k<3;k++) w_in_b[i + k*16384] = f2b(w_in[i + k*16384]);
    w_out_b[i]       = f2b(w_out[i]);
    w1_b[i]          = f2b(w1[i]);
    w1_b[i+16384]    = f2b(w1[i+16384]);
    w2_b[i]          = f2b(w2[i]);
    w2_b[i+16384]    = f2b(w2[i+16384]);
    hpw_b[i]         = f2b(hpw[i]);
    kvw_b[i]         = f2b(kvw[i]);
    kvw_b[i+16384]   = f2b(kvw[i+16384]);
    // transposed: qwT[c*128 + d] = qw[d*128 + c]
    qwT_b[i]         = f2b(qw[(i&127)*128 + (i>>7)]);
  }
}

// ---- node LN (over c) + fused hyperedge aggregation (MFMA agg) ----
// Register-exact LN: x held in f32 regs, stats+normalize exact; LDS tile is
// bf16 (f2b of exact LN) — bit-identical outputs to the f32-tile version.
// LDS 23.3 KB -> 7 blocks/CU; (256,5) -> ~20 waves/CU (was 16).
// BFOUT=1: bf16 [b][n][c] to nlnb. BFOUT=0: f32 c-major to nln.
template<int BFOUT, int AGG>
__global__ __launch_bounds__(256,5) void k_ln_agg(const float* __restrict__ fm,
                                                  const float* __restrict__ g,
                                                  const float* __restrict__ bb,
                                                  const float* __restrict__ sc,
                                                  float* __restrict__ nln,
                                                  bf_t* __restrict__ nlnb,
                                                  float* __restrict__ hacc){
  int b = blockIdx.y, n0 = blockIdx.x*64, tid = threadIdx.x;
  int lane = tid&63, wid = tid>>6, m16 = lane&15, quad = lane>>4;
  __shared__ __align__(16) bf_t xs[128*XR];   // [c][n] LN'd bf16, 18,432 B
  __shared__ bf_t scs[64][18];                // [n][e] bf16, 2,304 B
  __shared__ float pws[4][64], pwq[4][64];    // per-wave stat partials, 2,048 B
  __shared__ float mrs[2][64];                //   512 B  (total 23,296 B)
  const float* base = fm + (size_t)b*CC*NN + n0;
  int n4 = (tid&15)*4;

  // ---- stage fm into REGISTERS (exact f32) ----
  float4 xv[8];
  #pragma unroll
  for (int p=0;p<8;p++){
    int c = (tid>>4) + p*16;
    xv[p] = *(const float4*)(base + (size_t)c*NN + n4);
  }
  if (AGG){
    int n = tid>>2, e4 = (tid&3)*4;
    float4 sv = *(const float4*)(sc + ((size_t)(b*NN + n0 + n))*EE + e4);
    scs[n][e4+0] = f2b(sv.x); scs[n][e4+1] = f2b(sv.y);
    scs[n][e4+2] = f2b(sv.z); scs[n][e4+3] = f2b(sv.w);
  }

  // ---- LN stats from registers (exact) ----
  { float s4v[4]={0,0,0,0}, q4v[4]={0,0,0,0};
    #pragma unroll
    for (int p=0;p<8;p++){
      #pragma unroll
      for (int j=0;j<4;j++){
        float v = xv[p][j];
        s4v[j] += v; q4v[j] += v*v;
      }
    }
    // reduce lanes {k, k+16, k+32, k+48} within the wave
    #pragma unroll
    for (int j=0;j<4;j++){
      s4v[j] += __shfl_xor(s4v[j], 16, 64); q4v[j] += __shfl_xor(q4v[j], 16, 64);
      s4v[j] += __shfl_xor(s4v[j], 32, 64); q4v[j] += __shfl_xor(q4v[j], 32, 64);
    }
    if (lane < 16){
      #pragma unroll
      for (int j=0;j<4;j++){
        pws[wid][lane*4+j] = s4v[j];
        pwq[wid][lane*4+j] = q4v[j];
      }
    }
  }
  __syncthreads();
  if (tid < 64){
    float S = pws[0][tid]+pws[1][tid]+pws[2][tid]+pws[3][tid];
    float Q = pwq[0][tid]+pwq[1][tid]+pwq[2][tid]+pwq[3][tid];
    float m = S*(1.f/128.f);
    mrs[0][tid] = m; mrs[1][tid] = grs(Q*(1.f/128.f) - m*m);
  }
  __syncthreads();

  // ---- normalize from registers (exact), write bf16 to xs ----
  { float m0=mrs[0][n4+0], m1=mrs[0][n4+1], m2=mrs[0][n4+2], m3=mrs[0][n4+3];
    float r0=mrs[1][n4+0], r1=mrs[1][n4+1], r2=mrs[1][n4+2], r3=mrs[1][n4+3];
    #pragma unroll
    for (int p=0;p<8;p++){
      int c = (tid>>4) + p*16;
      float gv = g[c], bv = bb[c];
      float o0 = (xv[p][0]-m0)*r0*gv + bv;
      float o1 = (xv[p][1]-m1)*r1*gv + bv;
      float o2 = (xv[p][2]-m2)*r2*gv + bv;
      float o3 = (xv[p][3]-m3)*r3*gv + bv;
      u32 w0 = (u32)f2b(o0) | ((u32)f2b(o1)<<16);
      u32 w1 = (u32)f2b(o2) | ((u32)f2b(o3)<<16);
      *(u32*)&xs[c*XR + n4]     = w0;
      *(u32*)&xs[c*XR + n4 + 2] = w1;
      if (!BFOUT){
        float4 o; o.x=o0; o.y=o1; o.z=o2; o.w=o3;
        *(float4*)(nln + ((size_t)(b*CC + c))*NN + n0 + n4) = o;
      }
    }
  }
  __syncthreads();

  if (BFOUT){
    // bf16 [n][c] store: values = f2b(LN_exact), identical to prior version
    #pragma unroll
    for (int p=0;p<4;p++){
      int idx = tid + p*256;                // 0..1023
      int n = idx>>4, c8 = (idx&15)*8;
      short8 o;
      #pragma unroll
      for (int j=0;j<8;j++) o[j] = (short)xs[(c8+j)*XR + n];
      *(short8*)(nlnb + ((size_t)(b*NN + n0 + n))*CC + c8) = o;
    }
  }
  if (AGG){
    // sc^T @ xln via MFMA: D[e][c] += sum_n sc[n][e]*xln[c][n], K=64.
    short8 afr[2];
    #pragma unroll
    for (int k0=0;k0<2;k0++){
      short8 t;
      #pragma unroll
      for (int j=0;j<8;j++) t[j] = (short)scs[k0*32 + quad*8 + j][m16];
      afr[k0] = t;
    }
    #pragma unroll
    for (int u=0;u<2;u++){
      int ct0 = (wid + u*4)*16;             // 8 c-tiles over 4 waves x 2
      f32x4 acc = {0.f,0.f,0.f,0.f};
      #pragma unroll
      for (int k0=0;k0<2;k0++){
        short8 bfr = *(const short8*)&xs[(ct0+m16)*XR + k0*32 + quad*8];
        acc = __builtin_amdgcn_mfma_f32_16x16x32_bf16(afr[k0], bfr, acc, 0, 0, 0);
      }
      float* hb = hacc + ((size_t)(b*EE + quad*4))*CC + ct0 + m16;
      #pragma unroll
      for (int r=0;r<4;r++)
        atomicAdd(hb + (size_t)r*CC, acc[r]);
    }
  }
}

// ------- in-LDS 16-row MFMA GEMM helper (NW waves, tile-strided) -------
template<int K, int NOUT, int ACT, int WB, int NW>
__device__ __forceinline__ void gemm16(const bf_t* A, int SA,
                                       const float* __restrict__ W,
                                       const bf_t* __restrict__ Wb,
                                       const float* __restrict__ bias,
                                       bf_t* O, int SO, int tid){
  int lane = tid&63, wid = tid>>6;
  int m16 = lane&15, quad = lane>>4;
  for (int t0 = wid; t0 < NOUT/16; t0 += NW){
    int n0 = t0*16;
    f32x4 acc = {0.f,0.f,0.f,0.f};
    #pragma unroll
    for (int k0=0;k0<K;k0+=32){
      short8 af = *(const short8*)(A + m16*SA + k0 + quad*8);
      short8 bfv = WB ? *(const short8*)(Wb + (size_t)(n0+m16)*K + k0 + quad*8)
                      : ldw8(W + (size_t)(n0+m16)*K + k0 + quad*8);
      acc = __builtin_amdgcn_mfma_f32_16x16x32_bf16(af, bfv, acc, 0, 0, 0);
    }
    int col = n0 + m16;
    float bv = bias[col];
    #pragma unroll
    for (int r=0;r<4;r++){
      float v = acc[r] + bv;
      if (ACT) v = gelu_f(v);
      O[(quad*4+r)*SO + col] = f2b(v);
    }
  }
}

#define SP1 136
#define SP2 264
#define SP3 392

// -------- edge transformer (per batch), 512 threads = 8 waves --------
template<int WB>
__global__ __launch_bounds__(512) void k_edge(const float* __restrict__ hacc,
    const float* w_in, const float* b_in, const float* w_out, const float* b_out,
    const float* w1, const float* b1, const float* w2, const float* b2v,
    const float* tg, const float* tb, const float* nhg, const float* nhb,
    const float* hpw, const float* hpb, const float* kvw, const float* kvbias,
    const float* qw, const float* qb,
    const bf_t* __restrict__ w_in_b, const bf_t* __restrict__ w_out_b,
    const bf_t* __restrict__ w1_b, const bf_t* __restrict__ w2_b,
    const bf_t* __restrict__ hpw_b, const bf_t* __restrict__ kvw_b,
    const bf_t* __restrict__ qwT_b,
    bf_t* __restrict__ hfw, bf_t* __restrict__ vws,
    bf_t* __restrict__ Ktgb, float* __restrict__ qbK){
  __shared__ __align__(16) bf_t hyp0[16*SP1];
  __shared__ __align__(16) bf_t qkvb[16*SP3];
  __shared__ __align__(16) bf_t aob [16*SP1];
  __shared__ __align__(16) bf_t xnb [16*SP1];
  __shared__ __align__(16) bf_t h1b [16*SP2];
  __shared__ __align__(16) bf_t t2b [16*SP1];
  __shared__ __align__(16) bf_t hfb [16*SP1];
  __shared__ __align__(16) bf_t kvo [16*SP2];
  int b = blockIdx.x, tid = threadIdx.x;
  int lane = tid&63, wid = tid>>6, m16 = lane&15, quad = lane>>4;

  #pragma unroll
  for (int p=0;p<4;p++){
    int idx = tid + p*512;                  // 0..2047
    int e = idx>>7, c = idx&127;
    hyp0[e*SP1 + c] = f2b(hacc[(size_t)(b*EE + e)*CC + c]);
  }
  __syncthreads();
  gemm16<128,384,0,WB,8>(hyp0, SP1, w_in, w_in_b, b_in, qkvb, SP3, tid);
  __syncthreads();
  if (tid < 256){
    int part = tid&3, hq = tid>>2;
    int h = hq>>4, qi = hq&15;
    int dbase = h*32 + part*8;
    float qv[8];
    #pragma unroll
    for (int j=0;j<8;j++) qv[j] = b2f(qkvb[qi*SP3 + dbase + j]);
    float dot[16];
    #pragma unroll
    for (int kk=0;kk<16;kk++){
      float s = 0.f;
      #pragma unroll
      for (int j=0;j<8;j++) s += qv[j]*b2f(qkvb[kk*SP3 + 128 + dbase + j]);
      dot[kk] = s;
    }
    #pragma unroll
    for (int m=1;m<4;m<<=1){
      #pragma unroll
      for (int kk=0;kk<16;kk++) dot[kk] += __shfl_xor(dot[kk], m, 4);
    }
    const float sc1 = 0.17677669529663687f;
    float mx = -1e30f;
    #pragma unroll
    for (int kk=0;kk<16;kk++){ dot[kk] *= sc1; mx = fmaxf(mx, dot[kk]); }
    float sum = 0.f;
    #pragma unroll
    for (int kk=0;kk<16;kk++){ dot[kk] = __expf(dot[kk]-mx); sum += dot[kk]; }
    float inv = 1.f/sum;
    float ao[8] = {0,0,0,0,0,0,0,0};
    #pragma unroll
    for (int kk=0;kk<16;kk++){
      float p = dot[kk]*inv;
      #pragma unroll
      for (int j=0;j<8;j++) ao[j] += p*b2f(qkvb[kk*SP3 + 256 + dbase + j]);
    }
    #pragma unroll
    for (int j=0;j<8;j++) aob[qi*SP1 + dbase + j] = f2b(ao[j]);
  }
  __syncthreads();
  gemm16<128,128,0,WB,8>(aob, SP1, w_out, w_out_b, b_out, xnb, SP1, tid);
  __syncthreads();
  if (tid < 256){
    int e = tid>>4, i = tid&15;
    float v[8]; float s=0.f, q=0.f;
    #pragma unroll
    for (int j=0;j<8;j++){
      int c = i*8+j;
      v[j] = b2f(hyp0[e*SP1+c]) + b2f(xnb[e*SP1+c]);
      s += v[j]; q += v[j]*v[j];
    }
    s = red16(s); q = red16(q);
    float m = s*(1.f/128.f);
    float rs = grs(q*(1.f/128.f) - m*m);
    #pragma unroll
    for (int j=0;j<8;j++){
      int c = i*8+j;
      xnb[e*SP1+c] = f2b((v[j]-m)*rs*tg[c] + tb[c]);
    }
  }
  __syncthreads();
  gemm16<128,256,1,WB,8>(xnb, SP1, w1, w1_b, b1, h1b, SP2, tid);
  __syncthreads();
  gemm16<256,128,0,WB,8>(h1b, SP2, w2, w2_b, b2v, aob, SP1, tid);
  __syncthreads();
  if (tid < 256){
    int e = tid>>4, i = tid&15;
    float v[8]; float s=0.f, q=0.f;
    #pragma unroll
    for (int j=0;j<8;j++){
      int c = i*8+j;
      v[j] = b2f(xnb[e*SP1+c]) + b2f(aob[e*SP1+c]);
      s += v[j]; q += v[j]*v[j];
    }
    s = red16(s); q = red16(q);
    float m = s*(1.f/128.f);
    float rs = grs(q*(1.f/128.f) - m*m);
    float s2=0.f, q2=0.f;
    #pragma unroll
    for (int j=0;j<8;j++){
      int c = i*8+j;
      v[j] = (v[j]-m)*rs*tg[c] + tb[c];
      s2 += v[j]; q2 += v[j]*v[j];
    }
    s2 = red16(s2); q2 = red16(q2);
    float m2 = s2*(1.f/128.f);
    float rs2 = grs(q2*(1.f/128.f) - m2*m2);
    #pragma unroll
    for (int j=0;j<8;j++){
      int c = i*8+j;
      t2b[e*SP1+c] = f2b((v[j]-m2)*rs2*nhg[c] + nhb[c]);
    }
  }
  __syncthreads();
  gemm16<128,128,1,WB,8>(t2b, SP1, hpw, hpw_b, hpb, hfb, SP1, tid);
  __syncthreads();
  gemm16<128,256,0,WB,8>(hfb, SP1, kvw, kvw_b, kvbias, kvo, SP2, tid);
  __syncthreads();
  #pragma unroll
  for (int p=0;p<4;p++){
    int idx = tid + p*512;
    int e = idx>>7, c = idx&127;
    size_t o = (size_t)(b*EE + e)*CC + c;
    hfw[o] = hfb[e*SP1 + c];
    vws[o] = kvo[e*SP2 + 128 + c];
  }
  // Kt[e][c] = sum_d K[e][d]*qw[d][c] via MFMA, bf16 out (8 waves: 1 pass)
  {
    int n0 = wid*16;
    f32x4 acc = {0.f,0.f,0.f,0.f};
    #pragma unroll
    for (int k0=0;k0<128;k0+=32){
      short8 a = *(const short8*)(kvo + m16*SP2 + k0 + quad*8);
      short8 bq;
      if (WB){
        bq = *(const short8*)(qwT_b + (size_t)(n0+m16)*128 + k0 + quad*8);
      } else {
        #pragma unroll
        for (int j=0;j<8;j++)
          bq[j] = (short)f2b(qw[(size_t)(k0+quad*8+j)*128 + n0+m16]);
      }
      acc = __builtin_amdgcn_mfma_f32_16x16x32_bf16(a, bq, acc, 0, 0, 0);
    }
    #pragma unroll
    for (int r=0;r<4;r++)
      Ktgb[(size_t)(b*EE + quad*4 + r)*CC + n0 + m16] = f2b(acc[r]);
  }
  // qbK[e] = qb . K[e]
  if (tid < 256){
    int e = tid>>4, i = tid&15;
    float s = 0.f;
    #pragma unroll
    for (int j=0;j<8;j++) s += qb[i*8+j]*b2f(kvo[e*SP2 + i*8+j]);
    s = red16(s);
    if (i == 0) qbK[b*EE + e] = s;
  }
}

// -------- mega node kernel, 46.3 KB LDS; tail recompute-fuse (golden R10/R12) --------
template<int MODE>
__global__ __launch_bounds__(256,3) void k_meganode(
    float* __restrict__ io, const bf_t* __restrict__ nlnb,
    const float* __restrict__ sc,
    const bf_t* __restrict__ hf, const bf_t* __restrict__ vw,
    const bf_t* __restrict__ ktg, const float* __restrict__ qbK,
    const float* __restrict__ nfg, const float* __restrict__ nfb,
    const float* __restrict__ gw, const bf_t* __restrict__ gwb,
    const float* __restrict__ gb,
    const float* __restrict__ glng, const float* __restrict__ glnb,
    const float* __restrict__ npw, const bf_t* __restrict__ npwb,
    const float* __restrict__ npb){
  int tid = threadIdx.x, lane = tid&63, wid = tid>>6;
  int m16 = lane&15, quad = lane>>4;
  int b = blockIdx.y, n0 = blockIdx.x*64;
  __shared__ __align__(16) char sm[46336];
  bf_t* xt  = (bf_t*)(sm);            // [64][136] 17,408
  bf_t* ktT = (bf_t*)(sm + 17408);    // [16][136]  4,352 (dead after QK^T)
  bf_t* hfT = (bf_t*)(sm + 21760);    // [128][HS]  6,144 (LIVE to end: fuse recompute)
  bf_t* vfT = (bf_t*)(sm + 27904);    // [128][HS]  6,144 (LIVE to end)
  bf_t* ash = (bf_t*)(sm + 34048);    // [64][HS]   3,072
  bf_t* ct  = (bf_t*)(sm + 37120);    // [64][72]   9,216 (fresh; no live overlay)
  const short8 z8 = {0,0,0,0,0,0,0,0};

  // ---- staging ----
  if (MODE == 2){
    const bf_t* nb = nlnb + ((size_t)(b*NN + n0))*CC;
    #pragma unroll
    for (int p=0;p<4;p++){
      int idx = tid + p*256;                      // 0..1023
      int n = idx>>4, c8 = (idx&15)*8;
      *(short8*)&xt[n*136 + c8] = *(const short8*)(nb + (size_t)n*CC + c8);
    }
  } else {
    #pragma unroll
    for (int p=0;p<8;p++){
      int idx = tid + p*256;
      int c = idx>>4, n4 = (idx&15)*4;
      float4 v = *(const float4*)(io + ((size_t)(b*CC + c))*NN + n0 + n4);
      xt[(n4+0)*136 + c] = f2b(v.x);
      xt[(n4+1)*136 + c] = f2b(v.y);
      xt[(n4+2)*136 + c] = f2b(v.z);
      xt[(n4+3)*136 + c] = f2b(v.w);
    }
  }
  { const u32* kp = (const u32*)(ktg + (size_t)b*EE*CC);
    #pragma unroll
    for (int p=0;p<4;p++){
      int idx = tid + p*256;
      int e = idx>>6, c2 = (idx&63)*2;
      *(u32*)&ktT[e*136 + c2] = kp[idx];
    }
  }
  { const u32* hs = (const u32*)(hf + (size_t)b*EE*CC);
    const u32* vs = (const u32*)(vw + (size_t)b*EE*CC);
    #pragma unroll
    for (int p=0;p<4;p++){
      int idx = tid + p*256;
      int e = idx>>6, c2 = (idx&63)*2;
      u32 hv = hs[idx], vv = vs[idx];
      hfT[(c2+0)*HS + e] = (bf_t)(hv&0xffffu);
      hfT[(c2+1)*HS + e] = (bf_t)(hv>>16);
      vfT[(c2+0)*HS + e] = (bf_t)(vv&0xffffu);
      vfT[(c2+1)*HS + e] = (bf_t)(vv>>16);
    }
  }
  __syncthreads();

  // ---- QK^T via MFMA: D[node][e]; softmax over e ----
  f32x4 dacc = {0.f,0.f,0.f,0.f};
  #pragma unroll
  for (int kk=0;kk<4;kk++){
    short8 a = *(const short8*)(xt + (wid*16+m16)*136 + kk*32 + quad*8);
    short8 bfr = *(const short8*)(ktT + m16*136 + kk*32 + quad*8);
    dacc = __builtin_amdgcn_mfma_f32_16x16x32_bf16(a, bfr, dacc, 0, 0, 0);
  }
  { float qbe = qbK[b*EE + m16];
    #pragma unroll
    for (int r=0;r<4;r++){
      float v = (dacc[r] + qbe) * 0.08838834764831845f;   // C^-0.5
      float m = v;
      #pragma unroll
      for (int msk=1;msk<16;msk<<=1) m = fmaxf(m, __shfl_xor(m, msk, 16));
      float ex = __expf(v - m);
      float s = ex;
      #pragma unroll
      for (int msk=1;msk<16;msk<<=1) s += __shfl_xor(s, msk, 16);
      ash[(wid*16 + quad*4 + r)*HS + m16] = f2b(ex / s);
    }
  }

  // ---- intra = sc@hf, cross = a@vf via MFMA (K=16 in lower half) ----
  short8 scf = z8, asf = z8;
  if (quad < 2){
    const float* sp = sc + ((size_t)(b*NN + n0 + wid*16 + m16))*EE + quad*8;
    float4 u0 = *(const float4*)sp;
    float4 u1 = *(const float4*)(sp+4);
    scf[0]=(short)f2b(u0.x); scf[1]=(short)f2b(u0.y); scf[2]=(short)f2b(u0.z); scf[3]=(short)f2b(u0.w);
    scf[4]=(short)f2b(u1.x); scf[5]=(short)f2b(u1.y); scf[6]=(short)f2b(u1.z); scf[7]=(short)f2b(u1.w);
    asf = *(const short8*)(ash + (wid*16+m16)*HS + quad*8);
  }
  f32x4 acc_it[8], acc_cr[8];
  #pragma unroll
  for (int t=0;t<8;t++){
    short8 bh = z8, bv = z8;
    if (quad < 2){
      bh = *(const short8*)(hfT + (t*16+m16)*HS + quad*8);
      bv = *(const short8*)(vfT + (t*16+m16)*HS + quad*8);
    }
    f32x4 zf = {0.f,0.f,0.f,0.f};
    acc_it[t] = __builtin_amdgcn_mfma_f32_16x16x32_bf16(scf, bh, zf, 0, 0, 0);
    acc_cr[t] = __builtin_amdgcn_mfma_f32_16x16x32_bf16(asf, bv, zf, 0, 0, 0);
  }

  // ---- concat-LN stats (256 chans/node) ----
  float mean4[4], rstd4[4];
  { float s4[4]={0,0,0,0}, q4[4]={0,0,0,0};
    #pragma unroll
    for (int t=0;t<8;t++)
      #pragma unroll
      for (int r=0;r<4;r++){
        float a = acc_it[t][r], c = acc_cr[t][r];
        s4[r] += a + c; q4[r] += a*a + c*c;
      }
    #pragma unroll
    for (int r=0;r<4;r++){
      s4[r] = red16(s4[r]); q4[r] = red16(q4[r]);
      mean4[r] = s4[r]*(1.f/256.f);
      rstd4[r] = grs(q4[r]*(1.f/256.f) - mean4[r]*mean4[r]);
    }
  }
  __syncthreads();
  // ---- gate A fragments via ct [64][72], 64-channel sub-passes ----
  short8 af[8];
  #pragma unroll
  for (int s=0;s<2;s++){
    #pragma unroll
    for (int r=0;r<4;r++){
      int node = wid*16 + quad*4 + r;
      #pragma unroll
      for (int t=0;t<4;t++){
        int ch = (s*4+t)*16 + m16;
        ct[node*72 + t*16 + m16] = f2b((acc_it[s*4+t][r]-mean4[r])*rstd4[r]*nfg[ch] + nfb[ch]);
      }
    }
    #pragma unroll
    for (int k2=0;k2<2;k2++)
      af[s*2+k2] = *(const short8*)(ct + (wid*16+m16)*72 + k2*32 + quad*8);
  }
  #pragma unroll
  for (int s=0;s<2;s++){
    #pragma unroll
    for (int r=0;r<4;r++){
      int node = wid*16 + quad*4 + r;
      #pragma unroll
      for (int t=0;t<4;t++){
        int ch = (s*4+t)*16 + m16;
        ct[node*72 + t*16 + m16] = f2b((acc_cr[s*4+t][r]-mean4[r])*rstd4[r]*nfg[128+ch] + nfb[128+ch]);
      }
    }
    #pragma unroll
    for (int k2=0;k2<2;k2++)
      af[4+s*2+k2] = *(const short8*)(ct + (wid*16+m16)*72 + k2*32 + quad*8);
  }

  // ---- gate GEMM (K=256) ----
  f32x4 acc_g[8];
  #pragma unroll
  for (int t=0;t<8;t++){
    f32x4 a = {0.f,0.f,0.f,0.f};
    #pragma unroll
    for (int kk=0;kk<8;kk++){
      short8 w8 = (MODE >= 1) ? *(const short8*)(gwb + (size_t)(t*16+m16)*256 + kk*32 + quad*8)
                              : ldw8(gw + (size_t)(t*16+m16)*256 + kk*32 + quad*8);
      a = __builtin_amdgcn_mfma_f32_16x16x32_bf16(af[kk], w8, a, 0, 0, 0);
    }
    acc_g[t] = a;
  }

  // ---- gate bias + gate-LN stats ----
  float m2r[4], rs2r[4];
  { float s2[4]={0,0,0,0}, q2[4]={0,0,0,0};
    #pragma unroll
    for (int t=0;t<8;t++){
      float bv = gb[t*16+m16];
      #pragma unroll
      for (int r=0;r<4;r++){
        float v = acc_g[t][r] + bv;
        acc_g[t][r] = v; s2[r] += v; q2[r] += v*v;
      }
    }
    #pragma unroll
    for (int r=0;r<4;r++){
      s2[r] = red16(s2[r]); q2[r] = red16(q2[r]);
      m2r[r] = s2[r]*(1.f/128.f);
      rs2r[r] = grs(q2[r]*(1.f/128.f) - m2r[r]*m2r[r]);
    }
  }

  // ---- fuse: recompute it/cr per t (bitwise-identical MFMA), sigmoid gate,
  //      residual -> upd into xt ----
  #pragma unroll
  for (int t=0;t<8;t++){
    short8 bh = z8, bv = z8;
    if (quad < 2){
      bh = *(const short8*)(hfT + (t*16+m16)*HS + quad*8);
      bv = *(const short8*)(vfT + (t*16+m16)*HS + quad*8);
    }
    f32x4 zf = {0.f,0.f,0.f,0.f};
    f32x4 itR = __builtin_amdgcn_mfma_f32_16x16x32_bf16(scf, bh, zf, 0, 0, 0);
    f32x4 crR = __builtin_amdgcn_mfma_f32_16x16x32_bf16(asf, bv, zf, 0, 0, 0);
    int col = t*16 + m16;
    float lg = glng[col], lb = glnb[col];
    #pragma unroll
    for (int r=0;r<4;r++){
      float z = (acc_g[t][r]-m2r[r])*rs2r[r]*lg + lb;
      float gs = 1.f/(1.f + __expf(-z));
      int node = wid*16 + quad*4 + r;
      float nld = b2f(xt[node*136 + col]);
      xt[node*136 + col] = f2b(nld + gs*itR[r] + (1.f-gs)*crR[r]);
    }
  }

  // ---- output projection: frags from xt (wave-private rows), direct stores ----
  short8 bfu[4];
  #pragma unroll
  for (int kk=0;kk<4;kk++)
    bfu[kk] = *(const short8*)(xt + (wid*16+m16)*136 + kk*32 + quad*8);
  #pragma unroll
  for (int mt=0;mt<8;mt++){
    f32x4 o = {0.f,0.f,0.f,0.f};
    #pragma unroll
    for (int kk=0;kk<4;kk++){
      short8 aw = (MODE >= 1) ? *(const short8*)(npwb + (size_t)(mt*16+m16)*128 + kk*32 + quad*8)
                              : ldw8(npw + (size_t)(mt*16+m16)*128 + kk*32 + quad*8);
      o = __builtin_amdgcn_mfma_f32_16x16x32_bf16(aw, bfu[kk], o, 0, 0, 0);
    }
    #pragma unroll
    for (int r=0;r<4;r++){
      int cp = mt*16 + quad*4 + r;
      io[((size_t)(b*CC + cp))*NN + n0 + wid*16 + m16] = gelu_f(o[r] + npb[cp]);
    }
  }
}

extern "C" void kernel_launch(void* const* d_in, const int* in_sizes, int n_in,
                              void* d_out, int out_size, void* d_ws, size_t ws_size,
                              hipStream_t stream){
  (void)in_sizes; (void)n_in; (void)out_size;
  const float* fm   = (const float*)d_in[0];
  const float* sc   = (const float*)d_in[1];
  const float* npg  = (const float*)d_in[2];
  const float* npb_ = (const float*)d_in[3];
  const float* w_in = (const float*)d_in[4];
  const float* b_in = (const float*)d_in[5];
  const float* w_out= (const float*)d_in[6];
  const float* b_out= (const float*)d_in[7];
  const float* w1   = (const float*)d_in[8];
  const float* b1   = (const float*)d_in[9];
  const float* w2   = (const float*)d_in[10];
  const float* b2v  = (const float*)d_in[11];
  const float* tg   = (const float*)d_in[12];
  const float* tb   = (const float*)d_in[13];
  const float* nhg  = (const float*)d_in[14];
  const float* nhb  = (const float*)d_in[15];
  const float* hpw  = (const float*)d_in[16];
  const float* hpb  = (const float*)d_in[17];
  const float* qw   = (const float*)d_in[18];
  const float* qb   = (const float*)d_in[19];
  const float* kvw  = (const float*)d_in[20];
  const float* kvb  = (const float*)d_in[21];
  const float* nfg  = (const float*)d_in[22];
  const float* nfb  = (const float*)d_in[23];
  const float* gw   = (const float*)d_in[24];
  const float* gb   = (const float*)d_in[25];
  const float* glng = (const float*)d_in[26];
  const float* glnb = (const float*)d_in[27];
  const float* npw  = (const float*)d_in[28];
  const float* npb2 = (const float*)d_in[29];

  float* nln = (float*)d_out;   // fallback: f32 node tensor c-major lives in d_out

  // ws layout
  char* w = (char*)d_ws;
  float* hacc    = (float*)(w);             //  65,536 B
  float* qbK     = (float*)(w + 65536);     //     512 B
  bf_t*  hfw     = (bf_t*) (w + 66048);     //  32,768 B
  bf_t*  vws     = (bf_t*) (w + 98816);     //  32,768 B
  bf_t*  Ktgb    = (bf_t*) (w + 131584);    //  32,768 B (end 164,352)
  bf_t*  gwb     = (bf_t*) (w + 164352);    //  65,536 B
  bf_t*  npwb    = (bf_t*) (w + 229888);    //  32,768 B (end 262,656)
  bf_t*  w_in_b  = (bf_t*) (w + 262656);    //  98,304 B
  bf_t*  w_out_b = (bf_t*) (w + 360960);    //  32,768 B
  bf_t*  w1_b    = (bf_t*) (w + 393728);    //  65,536 B
  bf_t*  w2_b    = (bf_t*) (w + 459264);    //  65,536 B
  bf_t*  hpw_b   = (bf_t*) (w + 524800);    //  32,768 B
  bf_t*  kvw_b   = (bf_t*) (w + 557568);    //  65,536 B
  bf_t*  qwT_b   = (bf_t*) (w + 623104);    //  32,768 B (end 655,872)
  bf_t*  nlnb    = (bf_t*) (w + 655872);    // 18,874,368 B (end 19,530,240)
  bool full  = (ws_size >= (size_t)19530240);
  bool pre   = (ws_size >= (size_t)262656);

  if (full){
    k_pre<2><<<dim3(64), dim3(256), 0, stream>>>(hacc, gw, npw, gwb, npwb,
        w_in, w_out, w1, w2, hpw, kvw, qw,
        w_in_b, w_out_b, w1_b, w2_b, hpw_b, kvw_b, qwT_b);
    k_ln_agg<1,1><<<dim3(NT,8), dim3(256), 0, stream>>>(fm, npg, npb_, sc, nln, nlnb, hacc);
    k_edge<1><<<dim3(8), dim3(512), 0, stream>>>(hacc, w_in,b_in,w_out,b_out,
        w1,b1,w2,b2v, tg,tb, nhg,nhb, hpw,hpb, kvw,kvb, qw,qb,
        w_in_b, w_out_b, w1_b, w2_b, hpw_b, kvw_b, qwT_b,
        hfw, vws, Ktgb, qbK);
    k_meganode<2><<<dim3(NT,8), dim3(256), 0, stream>>>(nln, nlnb, sc, hfw, vws, Ktgb, qbK,
        nfg, nfb, gw, gwb, gb, glng, glnb, npw, npwb, npb2);
  } else if (pre){
    k_pre<1><<<dim3(64), dim3(256), 0, stream>>>(hacc, gw, npw, gwb, npwb,
        w_in, w_out, w1, w2, hpw, kvw, qw,
        w_in_b, w_out_b, w1_b, w2_b, hpw_b, kvw_b, qwT_b);
    k_ln_agg<0,1><<<dim3(NT,8), dim3(256), 0, stream>>>(fm, npg, npb_, sc, nln, nlnb, hacc);
    k_edge<0><<<dim3(8), dim3(512), 0, stream>>>(hacc, w_in,b_in,w_out,b_out,
        w1,b1,w2,b2v, tg,tb, nhg,nhb, hpw,hpb, kvw,kvb, qw,qb,
        w_in_b, w_out_b, w1_b, w2_b, hpw_b, kvw_b, qwT_b,
        hfw, vws, Ktgb, qbK);
    k_meganode<1><<<dim3(NT,8), dim3(256), 0, stream>>>(nln, nlnb, sc, hfw, vws, Ktgb, qbK,
        nfg, nfb, gw, gwb, gb, glng, glnb, npw, npwb, npb2);
  } else {
    k_pre<0><<<dim3(64), dim3(256), 0, stream>>>(hacc, gw, npw, gwb, npwb,
        w_in, w_out, w1, w2, hpw, kvw, qw,
        w_in_b, w_out_b, w1_b, w2_b, hpw_b, kvw_b, qwT_b);
    k_ln_agg<0,1><<<dim3(NT,8), dim3(256), 0, stream>>>(fm, npg, npb_, sc, nln, nlnb, hacc);
    k_edge<0><<<dim3(8), dim3(512), 0, stream>>>(hacc, w_in,b_in,w_out,b_out,
        w1,b1,w2,b2v, tg,tb, nhg,nhb, hpw,hpb, kvw,kvb, qw,qb,
        w_in_b, w_out_b, w1_b, w2_b, hpw_b, kvw_b, qwT_b,
        hfw, vws, Ktgb, qbK);
    k_meganode<0><<<dim3(NT,8), dim3(256), 0, stream>>>(nln, nlnb, sc, hfw, vws, Ktgb, qbK,
        nfg, nfb, gw, gwb, gb, glng, glnb, npw, npwb, npb2);
  }
}

// Round 15
// 251.636 us; speedup vs baseline: 1.0116x; 1.0030x over previous
//
#include <hip/hip_runtime.h>

typedef unsigned short bf_t;
typedef unsigned int u32;
typedef short short8 __attribute__((ext_vector_type(8)));
typedef float f32x4 __attribute__((ext_vector_type(4)));

#define NB 8
#define CC 128
#define NN 9216
#define EE 16
#define NT 144    // meganode n-tiles per batch (9216/64)
#define NTB 72    // ln_agg n-tiles per batch (9216/128)
#define HS 24     // hfT/vfT/ash padded row stride
#define XR2 136   // ln_agg xs row stride in bf16 (272B, 16B-aligned)

__device__ __forceinline__ float b2f(bf_t u){ return __uint_as_float(((u32)u)<<16); }
__device__ __forceinline__ bf_t f2b(float f){
  u32 u = __float_as_uint(f);
  u = (u + 0x7fffu + ((u>>16)&1u)) >> 16;
  return (bf_t)u;
}
__device__ __forceinline__ float gelu_f(float x){ return 0.5f*x*(1.f+erff(x*0.70710678118654752f)); }
__device__ __forceinline__ float red16(float v){
  #pragma unroll
  for (int m=1;m<16;m<<=1) v += __shfl_xor(v, m, 16);
  return v;
}
__device__ __forceinline__ float grs(float var){
  return rsqrtf(fmaxf(var + 1e-5f, 1e-8f));
}
// 8 consecutive fp32 -> bf16x8 MFMA fragment (fallback / on-the-fly path)
__device__ __forceinline__ short8 ldw8(const float* __restrict__ p){
  float4 a = *(const float4*)p;
  float4 b = *(const float4*)(p+4);
  short8 o;
  o[0]=(short)f2b(a.x); o[1]=(short)f2b(a.y); o[2]=(short)f2b(a.z); o[3]=(short)f2b(a.w);
  o[4]=(short)f2b(b.x); o[5]=(short)f2b(b.y); o[6]=(short)f2b(b.z); o[7]=(short)f2b(b.w);
  return o;
}

// ---------------- zero hacc (+ optional weight pre-convert) ----------------
// MODE 0: zero only. MODE 1: + gate/nproj weights. MODE 2: + all edge weights.
template<int MODE>
__global__ __launch_bounds__(256) void k_pre(float* __restrict__ hacc,
    const float* __restrict__ gw, const float* __restrict__ npw,
    bf_t* __restrict__ gwb, bf_t* __restrict__ npwb,
    const float* __restrict__ w_in, const float* __restrict__ w_out,
    const float* __restrict__ w1, const float* __restrict__ w2,
    const float* __restrict__ hpw, const float* __restrict__ kvw,
    const float* __restrict__ qw,
    bf_t* __restrict__ w_in_b, bf_t* __restrict__ w_out_b,
    bf_t* __restrict__ w1_b, bf_t* __restrict__ w2_b,
    bf_t* __restrict__ hpw_b, bf_t* __restrict__ kvw_b,
    bf_t* __restrict__ qwT_b){
  int i = blockIdx.x*256 + threadIdx.x;     // 64 blocks -> 16384
  hacc[i] = 0.f;
  if (MODE >= 1){
    gwb[i]       = f2b(gw[i]);
    gwb[i+16384] = f2b(gw[i+16384]);
    npwb[i]      = f2b(npw[i]);
  }
  if (MODE == 2){
    #pragma unroll
    for (int k=0;k<3;k++) w_in_b[i + k*16384] = f2b(w_in[i + k*16384]);
    w_out_b[i]       = f2b(w_out[i]);
    w1_b[i]          = f2b(w1[i]);
    w1_b[i+16384]    = f2b(w1[i+16384]);
    w2_b[i]          = f2b(w2[i]);
    w2_b[i+16384]    = f2b(w2[i+16384]);
    hpw_b[i]         = f2b(hpw[i]);
    kvw_b[i]         = f2b(kvw[i]);
    kvw_b[i+16384]   = f2b(kvw[i+16384]);
    // transposed: qwT[c*128 + d] = qw[d*128 + c]
    qwT_b[i]         = f2b(qw[(i&127)*128 + (i>>7)]);
  }
}

// ---- node LN (over c) + fused hyperedge aggregation (MFMA agg) ----
// 128-node tiles (grid 72x8): 16 in-flight loads/thread (2x MLP), half the
// barrier-drain sequences and atomics vs 64-node tiles. Register-exact LN
// (bit-identical values to prior versions). LDS 48.6 KB -> 3 blocks/CU
// (grid avg 2.25/CU: fully resident).
template<int BFOUT, int AGG>
__global__ __launch_bounds__(256,3) void k_ln_agg(const float* __restrict__ fm,
                                                  const float* __restrict__ g,
                                                  const float* __restrict__ bb,
                                                  const float* __restrict__ sc,
                                                  float* __restrict__ nln,
                                                  bf_t* __restrict__ nlnb,
                                                  float* __restrict__ hacc){
  int b = blockIdx.y, n0 = blockIdx.x*128, tid = threadIdx.x;
  int lane = tid&63, wid = tid>>6, m16 = lane&15, quad = lane>>4;
  __shared__ __align__(16) bf_t xs[128*XR2];   // [c][n] LN'd bf16, 34,816 B
  __shared__ bf_t scs[128][18];                // [n][e] bf16,       4,608 B
  __shared__ float pws[8][128], pwq[8][128];   // stat partials,     8,192 B
  __shared__ float mrs[2][128];                //                    1,024 B
  const float* base = fm + (size_t)b*CC*NN + n0;
  int ng = tid & 31, n4 = ng*4, cg = tid>>5;   // 32 node-groups x 8 c-groups

  // ---- stage fm into REGISTERS (16 float4 in flight) ----
  float4 xv[16];
  #pragma unroll
  for (int p=0;p<16;p++){
    int c = cg + p*8;
    xv[p] = *(const float4*)(base + (size_t)c*NN + n4);
  }
  if (AGG){
    #pragma unroll
    for (int p=0;p<2;p++){
      int idx = tid + p*256;                   // 0..511
      int n = idx>>2, e4 = (idx&3)*4;
      float4 sv = *(const float4*)(sc + ((size_t)(b*NN + n0 + n))*EE + e4);
      scs[n][e4+0] = f2b(sv.x); scs[n][e4+1] = f2b(sv.y);
      scs[n][e4+2] = f2b(sv.z); scs[n][e4+3] = f2b(sv.w);
    }
  }

  // ---- LN stats from registers (exact f32) ----
  { float s4v[4]={0,0,0,0}, q4v[4]={0,0,0,0};
    #pragma unroll
    for (int p=0;p<16;p++)
      #pragma unroll
      for (int j=0;j<4;j++){ float v = xv[p][j]; s4v[j]+=v; q4v[j]+=v*v; }
    #pragma unroll
    for (int j=0;j<4;j++){ pws[cg][n4+j]=s4v[j]; pwq[cg][n4+j]=q4v[j]; }
  }
  __syncthreads();
  if (tid < 128){
    float S=0.f, Q=0.f;
    #pragma unroll
    for (int k=0;k<8;k++){ S += pws[k][tid]; Q += pwq[k][tid]; }
    float m = S*(1.f/128.f);
    mrs[0][tid] = m; mrs[1][tid] = grs(Q*(1.f/128.f) - m*m);
  }
  __syncthreads();

  // ---- normalize from registers (exact), write bf16 to xs ----
  { float m0=mrs[0][n4+0], m1=mrs[0][n4+1], m2=mrs[0][n4+2], m3=mrs[0][n4+3];
    float r0=mrs[1][n4+0], r1=mrs[1][n4+1], r2=mrs[1][n4+2], r3=mrs[1][n4+3];
    #pragma unroll
    for (int p=0;p<16;p++){
      int c = cg + p*8;
      float gv = g[c], bv = bb[c];
      float o0 = (xv[p][0]-m0)*r0*gv + bv;
      float o1 = (xv[p][1]-m1)*r1*gv + bv;
      float o2 = (xv[p][2]-m2)*r2*gv + bv;
      float o3 = (xv[p][3]-m3)*r3*gv + bv;
      *(u32*)&xs[c*XR2 + n4]     = (u32)f2b(o0) | ((u32)f2b(o1)<<16);
      *(u32*)&xs[c*XR2 + n4 + 2] = (u32)f2b(o2) | ((u32)f2b(o3)<<16);
      if (!BFOUT){
        float4 o; o.x=o0; o.y=o1; o.z=o2; o.w=o3;
        *(float4*)(nln + ((size_t)(b*CC + c))*NN + n0 + n4) = o;
      }
    }
  }
  __syncthreads();

  if (BFOUT){
    // bf16 [n][c] store: coalesced 16B/lane rows
    #pragma unroll
    for (int p=0;p<8;p++){
      int idx = tid + p*256;                   // 0..2047
      int n = idx>>4, c8 = (idx&15)*8;
      short8 o;
      #pragma unroll
      for (int j=0;j<8;j++) o[j] = (short)xs[(c8+j)*XR2 + n];
      *(short8*)(nlnb + ((size_t)(b*NN + n0 + n))*CC + c8) = o;
    }
  }
  if (AGG){
    // sc^T @ xln via MFMA: D[e][c] += sum_n sc[n][e]*xln[c][n], K=128.
    short8 afr[4];
    #pragma unroll
    for (int k0=0;k0<4;k0++){
      short8 t;
      #pragma unroll
      for (int j=0;j<8;j++) t[j] = (short)scs[k0*32 + quad*8 + j][m16];
      afr[k0] = t;
    }
    #pragma unroll
    for (int u=0;u<2;u++){
      int ct0 = (wid + u*4)*16;                // 8 c-tiles over 4 waves x 2
      f32x4 acc = {0.f,0.f,0.f,0.f};
      #pragma unroll
      for (int k0=0;k0<4;k0++){
        short8 bfr = *(const short8*)&xs[(ct0+m16)*XR2 + k0*32 + quad*8];
        acc = __builtin_amdgcn_mfma_f32_16x16x32_bf16(afr[k0], bfr, acc, 0, 0, 0);
      }
      float* hb = hacc + ((size_t)(b*EE + quad*4))*CC + ct0 + m16;
      #pragma unroll
      for (int r=0;r<4;r++)
        atomicAdd(hb + (size_t)r*CC, acc[r]);
    }
  }
}

// ------- in-LDS 16-row MFMA GEMM helper (NW waves, tile-strided) -------
template<int K, int NOUT, int ACT, int WB, int NW>
__device__ __forceinline__ void gemm16(const bf_t* A, int SA,
                                       const float* __restrict__ W,
                                       const bf_t* __restrict__ Wb,
                                       const float* __restrict__ bias,
                                       bf_t* O, int SO, int tid){
  int lane = tid&63, wid = tid>>6;
  int m16 = lane&15, quad = lane>>4;
  for (int t0 = wid; t0 < NOUT/16; t0 += NW){
    int n0 = t0*16;
    f32x4 acc = {0.f,0.f,0.f,0.f};
    #pragma unroll
    for (int k0=0;k0<K;k0+=32){
      short8 af = *(const short8*)(A + m16*SA + k0 + quad*8);
      short8 bfv = WB ? *(const short8*)(Wb + (size_t)(n0+m16)*K + k0 + quad*8)
                      : ldw8(W + (size_t)(n0+m16)*K + k0 + quad*8);
      acc = __builtin_amdgcn_mfma_f32_16x16x32_bf16(af, bfv, acc, 0, 0, 0);
    }
    int col = n0 + m16;
    float bv = bias[col];
    #pragma unroll
    for (int r=0;r<4;r++){
      float v = acc[r] + bv;
      if (ACT) v = gelu_f(v);
      O[(quad*4+r)*SO + col] = f2b(v);
    }
  }
}

#define SP1 136
#define SP2 264
#define SP3 392

// -------- edge transformer (per batch), 512 threads = 8 waves --------
template<int WB>
__global__ __launch_bounds__(512) void k_edge(const float* __restrict__ hacc,
    const float* w_in, const float* b_in, const float* w_out, const float* b_out,
    const float* w1, const float* b1, const float* w2, const float* b2v,
    const float* tg, const float* tb, const float* nhg, const float* nhb,
    const float* hpw, const float* hpb, const float* kvw, const float* kvbias,
    const float* qw, const float* qb,
    const bf_t* __restrict__ w_in_b, const bf_t* __restrict__ w_out_b,
    const bf_t* __restrict__ w1_b, const bf_t* __restrict__ w2_b,
    const bf_t* __restrict__ hpw_b, const bf_t* __restrict__ kvw_b,
    const bf_t* __restrict__ qwT_b,
    bf_t* __restrict__ hfw, bf_t* __restrict__ vws,
    bf_t* __restrict__ Ktgb, float* __restrict__ qbK){
  __shared__ __align__(16) bf_t hyp0[16*SP1];
  __shared__ __align__(16) bf_t qkvb[16*SP3];
  __shared__ __align__(16) bf_t aob [16*SP1];
  __shared__ __align__(16) bf_t xnb [16*SP1];
  __shared__ __align__(16) bf_t h1b [16*SP2];
  __shared__ __align__(16) bf_t t2b [16*SP1];
  __shared__ __align__(16) bf_t hfb [16*SP1];
  __shared__ __align__(16) bf_t kvo [16*SP2];
  int b = blockIdx.x, tid = threadIdx.x;
  int lane = tid&63, wid = tid>>6, m16 = lane&15, quad = lane>>4;

  #pragma unroll
  for (int p=0;p<4;p++){
    int idx = tid + p*512;                  // 0..2047
    int e = idx>>7, c = idx&127;
    hyp0[e*SP1 + c] = f2b(hacc[(size_t)(b*EE + e)*CC + c]);
  }
  __syncthreads();
  gemm16<128,384,0,WB,8>(hyp0, SP1, w_in, w_in_b, b_in, qkvb, SP3, tid);
  __syncthreads();
  if (tid < 256){
    int part = tid&3, hq = tid>>2;
    int h = hq>>4, qi = hq&15;
    int dbase = h*32 + part*8;
    float qv[8];
    #pragma unroll
    for (int j=0;j<8;j++) qv[j] = b2f(qkvb[qi*SP3 + dbase + j]);
    float dot[16];
    #pragma unroll
    for (int kk=0;kk<16;kk++){
      float s = 0.f;
      #pragma unroll
      for (int j=0;j<8;j++) s += qv[j]*b2f(qkvb[kk*SP3 + 128 + dbase + j]);
      dot[kk] = s;
    }
    #pragma unroll
    for (int m=1;m<4;m<<=1){
      #pragma unroll
      for (int kk=0;kk<16;kk++) dot[kk] += __shfl_xor(dot[kk], m, 4);
    }
    const float sc1 = 0.17677669529663687f;
    float mx = -1e30f;
    #pragma unroll
    for (int kk=0;kk<16;kk++){ dot[kk] *= sc1; mx = fmaxf(mx, dot[kk]); }
    float sum = 0.f;
    #pragma unroll
    for (int kk=0;kk<16;kk++){ dot[kk] = __expf(dot[kk]-mx); sum += dot[kk]; }
    float inv = 1.f/sum;
    float ao[8] = {0,0,0,0,0,0,0,0};
    #pragma unroll
    for (int kk=0;kk<16;kk++){
      float p = dot[kk]*inv;
      #pragma unroll
      for (int j=0;j<8;j++) ao[j] += p*b2f(qkvb[kk*SP3 + 256 + dbase + j]);
    }
    #pragma unroll
    for (int j=0;j<8;j++) aob[qi*SP1 + dbase + j] = f2b(ao[j]);
  }
  __syncthreads();
  gemm16<128,128,0,WB,8>(aob, SP1, w_out, w_out_b, b_out, xnb, SP1, tid);
  __syncthreads();
  if (tid < 256){
    int e = tid>>4, i = tid&15;
    float v[8]; float s=0.f, q=0.f;
    #pragma unroll
    for (int j=0;j<8;j++){
      int c = i*8+j;
      v[j] = b2f(hyp0[e*SP1+c]) + b2f(xnb[e*SP1+c]);
      s += v[j]; q += v[j]*v[j];
    }
    s = red16(s); q = red16(q);
    float m = s*(1.f/128.f);
    float rs = grs(q*(1.f/128.f) - m*m);
    #pragma unroll
    for (int j=0;j<8;j++){
      int c = i*8+j;
      xnb[e*SP1+c] = f2b((v[j]-m)*rs*tg[c] + tb[c]);
    }
  }
  __syncthreads();
  gemm16<128,256,1,WB,8>(xnb, SP1, w1, w1_b, b1, h1b, SP2, tid);
  __syncthreads();
  gemm16<256,128,0,WB,8>(h1b, SP2, w2, w2_b, b2v, aob, SP1, tid);
  __syncthreads();
  if (tid < 256){
    int e = tid>>4, i = tid&15;
    float v[8]; float s=0.f, q=0.f;
    #pragma unroll
    for (int j=0;j<8;j++){
      int c = i*8+j;
      v[j] = b2f(xnb[e*SP1+c]) + b2f(aob[e*SP1+c]);
      s += v[j]; q += v[j]*v[j];
    }
    s = red16(s); q = red16(q);
    float m = s*(1.f/128.f);
    float rs = grs(q*(1.f/128.f) - m*m);
    float s2=0.f, q2=0.f;
    #pragma unroll
    for (int j=0;j<8;j++){
      int c = i*8+j;
      v[j] = (v[j]-m)*rs*tg[c] + tb[c];
      s2 += v[j]; q2 += v[j]*v[j];
    }
    s2 = red16(s2); q2 = red16(q2);
    float m2 = s2*(1.f/128.f);
    float rs2 = grs(q2*(1.f/128.f) - m2*m2);
    #pragma unroll
    for (int j=0;j<8;j++){
      int c = i*8+j;
      t2b[e*SP1+c] = f2b((v[j]-m2)*rs2*nhg[c] + nhb[c]);
    }
  }
  __syncthreads();
  gemm16<128,128,1,WB,8>(t2b, SP1, hpw, hpw_b, hpb, hfb, SP1, tid);
  __syncthreads();
  gemm16<128,256,0,WB,8>(hfb, SP1, kvw, kvw_b, kvbias, kvo, SP2, tid);
  __syncthreads();
  #pragma unroll
  for (int p=0;p<4;p++){
    int idx = tid + p*512;
    int e = idx>>7, c = idx&127;
    size_t o = (size_t)(b*EE + e)*CC + c;
    hfw[o] = hfb[e*SP1 + c];
    vws[o] = kvo[e*SP2 + 128 + c];
  }
  // Kt[e][c] = sum_d K[e][d]*qw[d][c] via MFMA, bf16 out (8 waves: 1 pass)
  {
    int n0 = wid*16;
    f32x4 acc = {0.f,0.f,0.f,0.f};
    #pragma unroll
    for (int k0=0;k0<128;k0+=32){
      short8 a = *(const short8*)(kvo + m16*SP2 + k0 + quad*8);
      short8 bq;
      if (WB){
        bq = *(const short8*)(qwT_b + (size_t)(n0+m16)*128 + k0 + quad*8);
      } else {
        #pragma unroll
        for (int j=0;j<8;j++)
          bq[j] = (short)f2b(qw[(size_t)(k0+quad*8+j)*128 + n0+m16]);
      }
      acc = __builtin_amdgcn_mfma_f32_16x16x32_bf16(a, bq, acc, 0, 0, 0);
    }
    #pragma unroll
    for (int r=0;r<4;r++)
      Ktgb[(size_t)(b*EE + quad*4 + r)*CC + n0 + m16] = f2b(acc[r]);
  }
  // qbK[e] = qb . K[e]
  if (tid < 256){
    int e = tid>>4, i = tid&15;
    float s = 0.f;
    #pragma unroll
    for (int j=0;j<8;j++) s += qb[i*8+j]*b2f(kvo[e*SP2 + i*8+j]);
    s = red16(s);
    if (i == 0) qbK[b*EE + e] = s;
  }
}

// -------- mega node kernel, 46.3 KB LDS; tail recompute-fuse (golden R10/R12) --------
template<int MODE>
__global__ __launch_bounds__(256,3) void k_meganode(
    float* __restrict__ io, const bf_t* __restrict__ nlnb,
    const float* __restrict__ sc,
    const bf_t* __restrict__ hf, const bf_t* __restrict__ vw,
    const bf_t* __restrict__ ktg, const float* __restrict__ qbK,
    const float* __restrict__ nfg, const float* __restrict__ nfb,
    const float* __restrict__ gw, const bf_t* __restrict__ gwb,
    const float* __restrict__ gb,
    const float* __restrict__ glng, const float* __restrict__ glnb,
    const float* __restrict__ npw, const bf_t* __restrict__ npwb,
    const float* __restrict__ npb){
  int tid = threadIdx.x, lane = tid&63, wid = tid>>6;
  int m16 = lane&15, quad = lane>>4;
  int b = blockIdx.y, n0 = blockIdx.x*64;
  __shared__ __align__(16) char sm[46336];
  bf_t* xt  = (bf_t*)(sm);            // [64][136] 17,408
  bf_t* ktT = (bf_t*)(sm + 17408);    // [16][136]  4,352 (dead after QK^T)
  bf_t* hfT = (bf_t*)(sm + 21760);    // [128][HS]  6,144 (LIVE to end: fuse recompute)
  bf_t* vfT = (bf_t*)(sm + 27904);    // [128][HS]  6,144 (LIVE to end)
  bf_t* ash = (bf_t*)(sm + 34048);    // [64][HS]   3,072
  bf_t* ct  = (bf_t*)(sm + 37120);    // [64][72]   9,216 (fresh; no live overlay)
  const short8 z8 = {0,0,0,0,0,0,0,0};

  // ---- staging ----
  if (MODE == 2){
    const bf_t* nb = nlnb + ((size_t)(b*NN + n0))*CC;
    #pragma unroll
    for (int p=0;p<4;p++){
      int idx = tid + p*256;                      // 0..1023
      int n = idx>>4, c8 = (idx&15)*8;
      *(short8*)&xt[n*136 + c8] = *(const short8*)(nb + (size_t)n*CC + c8);
    }
  } else {
    #pragma unroll
    for (int p=0;p<8;p++){
      int idx = tid + p*256;
      int c = idx>>4, n4 = (idx&15)*4;
      float4 v = *(const float4*)(io + ((size_t)(b*CC + c))*NN + n0 + n4);
      xt[(n4+0)*136 + c] = f2b(v.x);
      xt[(n4+1)*136 + c] = f2b(v.y);
      xt[(n4+2)*136 + c] = f2b(v.z);
      xt[(n4+3)*136 + c] = f2b(v.w);
    }
  }
  { const u32* kp = (const u32*)(ktg + (size_t)b*EE*CC);
    #pragma unroll
    for (int p=0;p<4;p++){
      int idx = tid + p*256;
      int e = idx>>6, c2 = (idx&63)*2;
      *(u32*)&ktT[e*136 + c2] = kp[idx];
    }
  }
  { const u32* hs = (const u32*)(hf + (size_t)b*EE*CC);
    const u32* vs = (const u32*)(vw + (size_t)b*EE*CC);
    #pragma unroll
    for (int p=0;p<4;p++){
      int idx = tid + p*256;
      int e = idx>>6, c2 = (idx&63)*2;
      u32 hv = hs[idx], vv = vs[idx];
      hfT[(c2+0)*HS + e] = (bf_t)(hv&0xffffu);
      hfT[(c2+1)*HS + e] = (bf_t)(hv>>16);
      vfT[(c2+0)*HS + e] = (bf_t)(vv&0xffffu);
      vfT[(c2+1)*HS + e] = (bf_t)(vv>>16);
    }
  }
  __syncthreads();

  // ---- QK^T via MFMA: D[node][e]; softmax over e ----
  f32x4 dacc = {0.f,0.f,0.f,0.f};
  #pragma unroll
  for (int kk=0;kk<4;kk++){
    short8 a = *(const short8*)(xt + (wid*16+m16)*136 + kk*32 + quad*8);
    short8 bfr = *(const short8*)(ktT + m16*136 + kk*32 + quad*8);
    dacc = __builtin_amdgcn_mfma_f32_16x16x32_bf16(a, bfr, dacc, 0, 0, 0);
  }
  { float qbe = qbK[b*EE + m16];
    #pragma unroll
    for (int r=0;r<4;r++){
      float v = (dacc[r] + qbe) * 0.08838834764831845f;   // C^-0.5
      float m = v;
      #pragma unroll
      for (int msk=1;msk<16;msk<<=1) m = fmaxf(m, __shfl_xor(m, msk, 16));
      float ex = __expf(v - m);
      float s = ex;
      #pragma unroll
      for (int msk=1;msk<16;msk<<=1) s += __shfl_xor(s, msk, 16);
      ash[(wid*16 + quad*4 + r)*HS + m16] = f2b(ex / s);
    }
  }

  // ---- intra = sc@hf, cross = a@vf via MFMA (K=16 in lower half) ----
  short8 scf = z8, asf = z8;
  if (quad < 2){
    const float* sp = sc + ((size_t)(b*NN + n0 + wid*16 + m16))*EE + quad*8;
    float4 u0 = *(const float4*)sp;
    float4 u1 = *(const float4*)(sp+4);
    scf[0]=(short)f2b(u0.x); scf[1]=(short)f2b(u0.y); scf[2]=(short)f2b(u0.z); scf[3]=(short)f2b(u0.w);
    scf[4]=(short)f2b(u1.x); scf[5]=(short)f2b(u1.y); scf[6]=(short)f2b(u1.z); scf[7]=(short)f2b(u1.w);
    asf = *(const short8*)(ash + (wid*16+m16)*HS + quad*8);
  }
  f32x4 acc_it[8], acc_cr[8];
  #pragma unroll
  for (int t=0;t<8;t++){
    short8 bh = z8, bv = z8;
    if (quad < 2){
      bh = *(const short8*)(hfT + (t*16+m16)*HS + quad*8);
      bv = *(const short8*)(vfT + (t*16+m16)*HS + quad*8);
    }
    f32x4 zf = {0.f,0.f,0.f,0.f};
    acc_it[t] = __builtin_amdgcn_mfma_f32_16x16x32_bf16(scf, bh, zf, 0, 0, 0);
    acc_cr[t] = __builtin_amdgcn_mfma_f32_16x16x32_bf16(asf, bv, zf, 0, 0, 0);
  }

  // ---- concat-LN stats (256 chans/node) ----
  float mean4[4], rstd4[4];
  { float s4[4]={0,0,0,0}, q4[4]={0,0,0,0};
    #pragma unroll
    for (int t=0;t<8;t++)
      #pragma unroll
      for (int r=0;r<4;r++){
        float a = acc_it[t][r], c = acc_cr[t][r];
        s4[r] += a + c; q4[r] += a*a + c*c;
      }
    #pragma unroll
    for (int r=0;r<4;r++){
      s4[r] = red16(s4[r]); q4[r] = red16(q4[r]);
      mean4[r] = s4[r]*(1.f/256.f);
      rstd4[r] = grs(q4[r]*(1.f/256.f) - mean4[r]*mean4[r]);
    }
  }
  __syncthreads();
  // ---- gate A fragments via ct [64][72], 64-channel sub-passes ----
  short8 af[8];
  #pragma unroll
  for (int s=0;s<2;s++){
    #pragma unroll
    for (int r=0;r<4;r++){
      int node = wid*16 + quad*4 + r;
      #pragma unroll
      for (int t=0;t<4;t++){
        int ch = (s*4+t)*16 + m16;
        ct[node*72 + t*16 + m16] = f2b((acc_it[s*4+t][r]-mean4[r])*rstd4[r]*nfg[ch] + nfb[ch]);
      }
    }
    #pragma unroll
    for (int k2=0;k2<2;k2++)
      af[s*2+k2] = *(const short8*)(ct + (wid*16+m16)*72 + k2*32 + quad*8);
  }
  #pragma unroll
  for (int s=0;s<2;s++){
    #pragma unroll
    for (int r=0;r<4;r++){
      int node = wid*16 + quad*4 + r;
      #pragma unroll
      for (int t=0;t<4;t++){
        int ch = (s*4+t)*16 + m16;
        ct[node*72 + t*16 + m16] = f2b((acc_cr[s*4+t][r]-mean4[r])*rstd4[r]*nfg[128+ch] + nfb[128+ch]);
      }
    }
    #pragma unroll
    for (int k2=0;k2<2;k2++)
      af[4+s*2+k2] = *(const short8*)(ct + (wid*16+m16)*72 + k2*32 + quad*8);
  }

  // ---- gate GEMM (K=256) ----
  f32x4 acc_g[8];
  #pragma unroll
  for (int t=0;t<8;t++){
    f32x4 a = {0.f,0.f,0.f,0.f};
    #pragma unroll
    for (int kk=0;kk<8;kk++){
      short8 w8 = (MODE >= 1) ? *(const short8*)(gwb + (size_t)(t*16+m16)*256 + kk*32 + quad*8)
                              : ldw8(gw + (size_t)(t*16+m16)*256 + kk*32 + quad*8);
      a = __builtin_amdgcn_mfma_f32_16x16x32_bf16(af[kk], w8, a, 0, 0, 0);
    }
    acc_g[t] = a;
  }

  // ---- gate bias + gate-LN stats ----
  float m2r[4], rs2r[4];
  { float s2[4]={0,0,0,0}, q2[4]={0,0,0,0};
    #pragma unroll
    for (int t=0;t<8;t++){
      float bv = gb[t*16+m16];
      #pragma unroll
      for (int r=0;r<4;r++){
        float v = acc_g[t][r] + bv;
        acc_g[t][r] = v; s2[r] += v; q2[r] += v*v;
      }
    }
    #pragma unroll
    for (int r=0;r<4;r++){
      s2[r] = red16(s2[r]); q2[r] = red16(q2[r]);
      m2r[r] = s2[r]*(1.f/128.f);
      rs2r[r] = grs(q2[r]*(1.f/128.f) - m2r[r]*m2r[r]);
    }
  }

  // ---- fuse: recompute it/cr per t (bitwise-identical MFMA), sigmoid gate,
  //      residual -> upd into xt ----
  #pragma unroll
  for (int t=0;t<8;t++){
    short8 bh = z8, bv = z8;
    if (quad < 2){
      bh = *(const short8*)(hfT + (t*16+m16)*HS + quad*8);
      bv = *(const short8*)(vfT + (t*16+m16)*HS + quad*8);
    }
    f32x4 zf = {0.f,0.f,0.f,0.f};
    f32x4 itR = __builtin_amdgcn_mfma_f32_16x16x32_bf16(scf, bh, zf, 0, 0, 0);
    f32x4 crR = __builtin_amdgcn_mfma_f32_16x16x32_bf16(asf, bv, zf, 0, 0, 0);
    int col = t*16 + m16;
    float lg = glng[col], lb = glnb[col];
    #pragma unroll
    for (int r=0;r<4;r++){
      float z = (acc_g[t][r]-m2r[r])*rs2r[r]*lg + lb;
      float gs = 1.f/(1.f + __expf(-z));
      int node = wid*16 + quad*4 + r;
      float nld = b2f(xt[node*136 + col]);
      xt[node*136 + col] = f2b(nld + gs*itR[r] + (1.f-gs)*crR[r]);
    }
  }

  // ---- output projection: frags from xt (wave-private rows), direct stores ----
  short8 bfu[4];
  #pragma unroll
  for (int kk=0;kk<4;kk++)
    bfu[kk] = *(const short8*)(xt + (wid*16+m16)*136 + kk*32 + quad*8);
  #pragma unroll
  for (int mt=0;mt<8;mt++){
    f32x4 o = {0.f,0.f,0.f,0.f};
    #pragma unroll
    for (int kk=0;kk<4;kk++){
      short8 aw = (MODE >= 1) ? *(const short8*)(npwb + (size_t)(mt*16+m16)*128 + kk*32 + quad*8)
                              : ldw8(npw + (size_t)(mt*16+m16)*128 + kk*32 + quad*8);
      o = __builtin_amdgcn_mfma_f32_16x16x32_bf16(aw, bfu[kk], o, 0, 0, 0);
    }
    #pragma unroll
    for (int r=0;r<4;r++){
      int cp = mt*16 + quad*4 + r;
      io[((size_t)(b*CC + cp))*NN + n0 + wid*16 + m16] = gelu_f(o[r] + npb[cp]);
    }
  }
}

extern "C" void kernel_launch(void* const* d_in, const int* in_sizes, int n_in,
                              void* d_out, int out_size, void* d_ws, size_t ws_size,
                              hipStream_t stream){
  (void)in_sizes; (void)n_in; (void)out_size;
  const float* fm   = (const float*)d_in[0];
  const float* sc   = (const float*)d_in[1];
  const float* npg  = (const float*)d_in[2];
  const float* npb_ = (const float*)d_in[3];
  const float* w_in = (const float*)d_in[4];
  const float* b_in = (const float*)d_in[5];
  const float* w_out= (const float*)d_in[6];
  const float* b_out= (const float*)d_in[7];
  const float* w1   = (const float*)d_in[8];
  const float* b1   = (const float*)d_in[9];
  const float* w2   = (const float*)d_in[10];
  const float* b2v  = (const float*)d_in[11];
  const float* tg   = (const float*)d_in[12];
  const float* tb   = (const float*)d_in[13];
  const float* nhg  = (const float*)d_in[14];
  const float* nhb  = (const float*)d_in[15];
  const float* hpw  = (const float*)d_in[16];
  const float* hpb  = (const float*)d_in[17];
  const float* qw   = (const float*)d_in[18];
  const float* qb   = (const float*)d_in[19];
  const float* kvw  = (const float*)d_in[20];
  const float* kvb  = (const float*)d_in[21];
  const float* nfg  = (const float*)d_in[22];
  const float* nfb  = (const float*)d_in[23];
  const float* gw   = (const float*)d_in[24];
  const float* gb   = (const float*)d_in[25];
  const float* glng = (const float*)d_in[26];
  const float* glnb = (const float*)d_in[27];
  const float* npw  = (const float*)d_in[28];
  const float* npb2 = (const float*)d_in[29];

  float* nln = (float*)d_out;   // fallback: f32 node tensor c-major lives in d_out

  // ws layout
  char* w = (char*)d_ws;
  float* hacc    = (float*)(w);             //  65,536 B
  float* qbK     = (float*)(w + 65536);     //     512 B
  bf_t*  hfw     = (bf_t*) (w + 66048);     //  32,768 B
  bf_t*  vws     = (bf_t*) (w + 98816);     //  32,768 B
  bf_t*  Ktgb    = (bf_t*) (w + 131584);    //  32,768 B (end 164,352)
  bf_t*  gwb     = (bf_t*) (w + 164352);    //  65,536 B
  bf_t*  npwb    = (bf_t*) (w + 229888);    //  32,768 B (end 262,656)
  bf_t*  w_in_b  = (bf_t*) (w + 262656);    //  98,304 B
  bf_t*  w_out_b = (bf_t*) (w + 360960);    //  32,768 B
  bf_t*  w1_b    = (bf_t*) (w + 393728);    //  65,536 B
  bf_t*  w2_b    = (bf_t*) (w + 459264);    //  65,536 B
  bf_t*  hpw_b   = (bf_t*) (w + 524800);    //  32,768 B
  bf_t*  kvw_b   = (bf_t*) (w + 557568);    //  65,536 B
  bf_t*  qwT_b   = (bf_t*) (w + 623104);    //  32,768 B (end 655,872)
  bf_t*  nlnb    = (bf_t*) (w + 655872);    // 18,874,368 B (end 19,530,240)
  bool full  = (ws_size >= (size_t)19530240);
  bool pre   = (ws_size >= (size_t)262656);

  if (full){
    k_pre<2><<<dim3(64), dim3(256), 0, stream>>>(hacc, gw, npw, gwb, npwb,
        w_in, w_out, w1, w2, hpw, kvw, qw,
        w_in_b, w_out_b, w1_b, w2_b, hpw_b, kvw_b, qwT_b);
    k_ln_agg<1,1><<<dim3(NTB,8), dim3(256), 0, stream>>>(fm, npg, npb_, sc, nln, nlnb, hacc);
    k_edge<1><<<dim3(8), dim3(512), 0, stream>>>(hacc, w_in,b_in,w_out,b_out,
        w1,b1,w2,b2v, tg,tb, nhg,nhb, hpw,hpb, kvw,kvb, qw,qb,
        w_in_b, w_out_b, w1_b, w2_b, hpw_b, kvw_b, qwT_b,
        hfw, vws, Ktgb, qbK);
    k_meganode<2><<<dim3(NT,8), dim3(256), 0, stream>>>(nln, nlnb, sc, hfw, vws, Ktgb, qbK,
        nfg, nfb, gw, gwb, gb, glng, glnb, npw, npwb, npb2);
  } else if (pre){
    k_pre<1><<<dim3(64), dim3(256), 0, stream>>>(hacc, gw, npw, gwb, npwb,
        w_in, w_out, w1, w2, hpw, kvw, qw,
        w_in_b, w_out_b, w1_b, w2_b, hpw_b, kvw_b, qwT_b);
    k_ln_agg<0,1><<<dim3(NTB,8), dim3(256), 0, stream>>>(fm, npg, npb_, sc, nln, nlnb, hacc);
    k_edge<0><<<dim3(8), dim3(512), 0, stream>>>(hacc, w_in,b_in,w_out,b_out,
        w1,b1,w2,b2v, tg,tb, nhg,nhb, hpw,hpb, kvw,kvb, qw,qb,
        w_in_b, w_out_b, w1_b, w2_b, hpw_b, kvw_b, qwT_b,
        hfw, vws, Ktgb, qbK);
    k_meganode<1><<<dim3(NT,8), dim3(256), 0, stream>>>(nln, nlnb, sc, hfw, vws, Ktgb, qbK,
        nfg, nfb, gw, gwb, gb, glng, glnb, npw, npwb, npb2);
  } else {
    k_pre<0><<<dim3(64), dim3(256), 0, stream>>>(hacc, gw, npw, gwb, npwb,
        w_in, w_out, w1, w2, hpw, kvw, qw,
        w_in_b, w_out_b, w1_b, w2_b, hpw_b, kvw_b, qwT_b);
    k_ln_agg<0,1><<<dim3(NTB,8), dim3(256), 0, stream>>>(fm, npg, npb_, sc, nln, nlnb, hacc);
    k_edge<0><<<dim3(8), dim3(512), 0, stream>>>(hacc, w_in,b_in,w_out,b_out,
        w1,b1,w2,b2v, tg,tb, nhg,nhb, hpw,hpb, kvw,kvb, qw,qb,
        w_in_b, w_out_b, w1_b, w2_b, hpw_b, kvw_b, qwT_b,
        hfw, vws, Ktgb, qbK);
    k_meganode<0><<<dim3(NT,8), dim3(256), 0, stream>>>(nln, nlnb, sc, hfw, vws, Ktgb, qbK,
        nfg, nfb, gw, gwb, gb, glng, glnb, npw, npwb, npb2);
  }
}